// Round 3
// baseline (636.653 us; speedup 1.0000x reference)
//
#include <hip/hip_runtime.h>
#include <hip/hip_bf16.h>
#include <math.h>

#define B_ 2
#define S_ 2048
#define D_ 1024
#define H_ 4
#define DK_ 256
#define NJ 24
#define NG 96
#define QT 32
#define KT 32
#define NT (S_ / KT)

typedef float v2f __attribute__((ext_vector_type(2)));

// ---------------- kernel 1: fold Wq into proj ----------------
// M[d][hj] = sum_k Wq_w[h*256+k][d] * proj_w[j][k]
__global__ __launch_bounds__(256) void k_fuse(const float* __restrict__ Wq_w,
                                              const float* __restrict__ proj_w,
                                              float* __restrict__ M) {
  int tid = blockIdx.x * 256 + threadIdx.x;  // 96*1024 threads
  int hj = tid >> 10;
  int d = tid & 1023;
  int h = hj / NJ, j = hj - h * NJ;
  const float* wq = Wq_w + (size_t)(h * DK_) * D_ + d;
  const float* pw = proj_w + j * DK_;
  float acc = 0.f;
#pragma unroll 8
  for (int k = 0; k < DK_; ++k) acc += wq[(size_t)k * D_] * pw[k];
  M[(size_t)d * NG + hj] = acc;
}

// cbias[hj] = sum_k Wq_b[h*256+k]*proj_w[j][k] + proj_b[j]
__global__ void k_fuse_bias(const float* __restrict__ Wq_b,
                            const float* __restrict__ proj_w,
                            const float* __restrict__ proj_b,
                            float* __restrict__ cbias) {
  int hj = threadIdx.x;
  if (hj < NG) {
    int h = hj / NJ, j = hj - h * NJ;
    float acc = proj_b[j];
    for (int k = 0; k < DK_; ++k) acc += Wq_b[h * DK_ + k] * proj_w[j * DK_ + k];
    cbias[hj] = acc;
  }
}

// ---------------- psi from gen rows (8 rows per block) ----------------
__device__ __forceinline__ void psi_store(const float (*genL)[NG], int t, int g0,
                                          float* __restrict__ po,
                                          float* __restrict__ n2o) {
  if (t < 64) {
    int h = t >> 4, ii = t & 15, j = ii & 7;
#pragma unroll 2
    for (int r = 0; r < 8; ++r) {
      int g = g0 + r;
      int b = g >> 11, s = g & (S_ - 1);
      const float* gl = genL[r] + h * NJ;
      float A = gl[j], Bg = gl[8 + j];
      float Th = fminf(fmaxf(gl[16 + j], -8.f), 8.f);
      float val = (ii < 8) ? (A * expf(Th) + Bg * cosf(Th)) : (Bg * sinf(Th));
      size_t base = (size_t)(b * H_ + h) * S_ + s;
      po[base * 16 + ii] = val;
      float sq = val * val;
#pragma unroll
      for (int off = 1; off < 16; off <<= 1) sq += __shfl_xor(sq, off);
      if (ii == 0) n2o[base] = sq;
    }
  }
}

// ---------------- gen_q = Q_input @ M + cbias, then psi ----------------
__global__ __launch_bounds__(128) void k_genq(const float* __restrict__ Q,
                                              const float* __restrict__ M,
                                              const float* __restrict__ cbias,
                                              float* __restrict__ pq,
                                              float* __restrict__ qn2) {
  __shared__ __align__(16) float qlds[8][D_];
  __shared__ float genL[8][NG];
  int t = threadIdx.x;
  int g0 = blockIdx.x * 8;
  {
    const float4* src = (const float4*)(Q + (size_t)g0 * D_);
    float4* dst = (float4*)&qlds[0][0];
#pragma unroll
    for (int u = 0; u < 16; ++u) dst[t + 128 * u] = src[t + 128 * u];
  }
  __syncthreads();
  if (t < NG) {
    float cb = cbias[t];
    float acc[8];
#pragma unroll
    for (int r = 0; r < 8; ++r) acc[r] = cb;
    const float* Mp = M + t;
#pragma unroll 2
    for (int d0 = 0; d0 < D_; d0 += 4) {
      float m0 = Mp[(size_t)(d0 + 0) * NG];
      float m1 = Mp[(size_t)(d0 + 1) * NG];
      float m2 = Mp[(size_t)(d0 + 2) * NG];
      float m3 = Mp[(size_t)(d0 + 3) * NG];
#pragma unroll
      for (int r = 0; r < 8; ++r) {
        float4 q4 = *(const float4*)&qlds[r][d0];
        acc[r] += q4.x * m0 + q4.y * m1 + q4.z * m2 + q4.w * m3;
      }
    }
#pragma unroll
    for (int r = 0; r < 8; ++r) genL[r][t] = acc[r];
  }
  __syncthreads();
  psi_store(genL, t, g0, pq, qn2);
}

// ---------------- gen_k = K_head @ proj_w.T + proj_b, then psi ----------------
__global__ __launch_bounds__(128) void k_genk(const float* __restrict__ Kin,
                                              const float* __restrict__ proj_w,
                                              const float* __restrict__ proj_b,
                                              float* __restrict__ pk,
                                              float* __restrict__ kn2) {
  __shared__ __align__(16) float klds[8][D_];
  __shared__ float genL[8][NG];
  __shared__ float pwT[DK_][NJ];
  int t = threadIdx.x;
  int g0 = blockIdx.x * 8;
  {
    const float4* src = (const float4*)(Kin + (size_t)g0 * D_);
    float4* dst = (float4*)&klds[0][0];
#pragma unroll
    for (int u = 0; u < 16; ++u) dst[t + 128 * u] = src[t + 128 * u];
  }
  for (int idx = t; idx < NJ * DK_; idx += 128) {
    int j = idx >> 8, c = idx & 255;
    pwT[c][j] = proj_w[idx];
  }
  __syncthreads();
  if (t < NG) {
    int h = t / NJ, j = t - h * NJ;
    float pb = proj_b[j];
    float acc[8];
#pragma unroll
    for (int r = 0; r < 8; ++r) acc[r] = pb;
#pragma unroll 2
    for (int c0 = 0; c0 < DK_; c0 += 4) {
      float w0 = pwT[c0][j], w1 = pwT[c0 + 1][j];
      float w2 = pwT[c0 + 2][j], w3 = pwT[c0 + 3][j];
#pragma unroll
      for (int r = 0; r < 8; ++r) {
        float4 k4 = *(const float4*)&klds[r][h * DK_ + c0];
        acc[r] += k4.x * w0 + k4.y * w1 + k4.z * w2 + k4.w * w3;
      }
    }
#pragma unroll
    for (int r = 0; r < 8; ++r) genL[r][t] = acc[r];
  }
  __syncthreads();
  psi_store(genL, t, g0, pk, kn2);
}

// ---------------- flash-style geometric attention ----------------
// 512 threads, KT=32, double-buffered staging, packed-f32 math.
// scores: sr = t>>4 (row 0..31), kd = t&15 -> 2 k's (kb=kd*2)
// PV:     rg = t&7 (rows rg*4..+3), cg = t>>3 (cols cg*4..+3)
__global__ __launch_bounds__(512, 4) void k_attn(
    const float* __restrict__ pq, const float* __restrict__ qn2,
    const float* __restrict__ pk, const float* __restrict__ kn2,
    const float* __restrict__ V, const float* __restrict__ geo_w,
    const float* __restrict__ temp, float* __restrict__ attn_out) {
  __shared__ __align__(16) float Vs[2][KT][256];   // 65536 B
  __shared__ __align__(16) float pkT[2][16][68];   // 8704 B
  __shared__ __align__(16) float Pt[KT][36];       // 4608 B (144B rows: b128-aligned)
  __shared__ __align__(16) float kn2s[2][KT], khs[2][KT];
  __shared__ float mL[QT], lL[QT], fL[QT];

  int t = threadIdx.x;
  int bid = blockIdx.x;
  int bh = bid & 7;           // XCD round-robin: same (b,h) -> same XCD L2
  int qt = bid >> 3;
  int h = bh & (H_ - 1);
  int b = bh >> 2;
  int q0 = qt * QT;
  const float* pqb = pq + ((size_t)bh * S_ + q0) * 16;
  const float* pkb = pk + (size_t)bh * S_ * 16;
  const float* kn2b = kn2 + (size_t)bh * S_;
  const float* Vb = V + (size_t)b * S_ * D_ + h * DK_;

  float g0w = geo_w[0], g1w = geo_w[1], g2w = geo_w[2], g3w = geo_w[3];
  float scale = 1.f / (4.f * temp[0]);

  // roles
  int sr = t >> 4, kd = t & 15, kb = kd * 2;
  int rg = t & 7, cg = t >> 3;
  int lane = t & 63, vw = t >> 6;
  bool dopk = (t < 128);
  int pr_ = t >> 2, ps_ = t & 3;
  bool dokn = (t < 8);

  // q row in registers
  float qreg[16];
  {
    const float4* qp = (const float4*)(pqb + (size_t)sr * 16);
#pragma unroll
    for (int i = 0; i < 4; ++i) {
      float4 v = qp[i];
      qreg[i * 4 + 0] = v.x; qreg[i * 4 + 1] = v.y;
      qreg[i * 4 + 2] = v.z; qreg[i * 4 + 3] = v.w;
    }
  }
  float myqn2 = 0.f;
#pragma unroll
  for (int i = 0; i < 16; ++i) myqn2 += qreg[i] * qreg[i];
  float myqh = sqrtf(myqn2 + 1e-6f);

  if (t < QT) { mL[t] = -INFINITY; lL[t] = 0.f; }

  v2f acc2[4][2];
#pragma unroll
  for (int i = 0; i < 4; ++i) {
    acc2[i][0] = (v2f){0.f, 0.f};
    acc2[i][1] = (v2f){0.f, 0.f};
  }

  // ---- prologue: stage tile 0 into buffer 0 ----
  {
    float4 vreg[4];
    const float* src = Vb + (size_t)(vw * 4) * D_ + lane * 4;
#pragma unroll
    for (int u = 0; u < 4; ++u) vreg[u] = *(const float4*)(src + (size_t)u * D_);
    float4 pkreg;
    if (dopk) pkreg = *(const float4*)(pkb + (size_t)pr_ * 16 + ps_ * 4);
    float4 knreg;
    if (dokn) knreg = *(const float4*)(kn2b + t * 4);
#pragma unroll
    for (int u = 0; u < 4; ++u) *(float4*)&Vs[0][vw * 4 + u][lane * 4] = vreg[u];
    if (dopk) {
      pkT[0][ps_ * 4 + 0][pr_] = pkreg.x;
      pkT[0][ps_ * 4 + 1][pr_] = pkreg.y;
      pkT[0][ps_ * 4 + 2][pr_] = pkreg.z;
      pkT[0][ps_ * 4 + 3][pr_] = pkreg.w;
    }
    if (dokn) {
      kn2s[0][t * 4 + 0] = knreg.x; khs[0][t * 4 + 0] = sqrtf(knreg.x + 1e-6f);
      kn2s[0][t * 4 + 1] = knreg.y; khs[0][t * 4 + 1] = sqrtf(knreg.y + 1e-6f);
      kn2s[0][t * 4 + 2] = knreg.z; khs[0][t * 4 + 2] = sqrtf(knreg.z + 1e-6f);
      kn2s[0][t * 4 + 3] = knreg.w; khs[0][t * 4 + 3] = sqrtf(knreg.w + 1e-6f);
    }
  }
  __syncthreads();

  int cur = 0;
  for (int kt = 0; kt < NT; ++kt) {
    int k0 = kt * KT;
    int nb = cur ^ 1;
    // ---- issue next-tile loads (regs) early: latency hides under scores ----
    float4 vreg[4], pkreg, knreg;
    if (kt + 1 < NT) {
      int k0n = k0 + KT;
      const float* src = Vb + (size_t)(k0n + vw * 4) * D_ + lane * 4;
#pragma unroll
      for (int u = 0; u < 4; ++u) vreg[u] = *(const float4*)(src + (size_t)u * D_);
      if (dopk) pkreg = *(const float4*)(pkb + (size_t)(k0n + pr_) * 16 + ps_ * 4);
      if (dokn) knreg = *(const float4*)(kn2b + k0n + t * 4);
    }

    // ---- scores from buffer cur ----
    {
      const float(*pkc)[68] = pkT[cur];
      v2f tn = {0.f, 0.f}, sp = {0.f, 0.f};
#pragma unroll
      for (int i = 0; i < 8; ++i) {
        v2f ka = *(const v2f*)&pkc[i][kb];
        v2f kc = *(const v2f*)&pkc[i + 8][kb];
        float qa = qreg[i], qb = qreg[i + 8];
        tn += qa * ka + qb * kc;
        sp += qa * kc - qb * ka;
      }
      v2f kn2v = *(const v2f*)&kn2s[cur][kb];
      v2f khv = *(const v2f*)&khs[cur][kb];
      v2f wraw = myqn2 * kn2v - tn * tn - sp * sp;
      float w0 = sqrtf(fmaxf(wraw.x, 0.f) + 1e-6f);
      float w1 = sqrtf(fmaxf(wraw.y, 0.f) + 1e-6f);
      float sv0 = (g0w * w0 + g1w * tn.x + g2w * sp.x + g3w * (myqh * khv.x)) * scale;
      float sv1 = (g0w * w1 + g1w * tn.y + g2w * sp.y + g3w * (myqh * khv.y)) * scale;
      float tmax = fmaxf(sv0, sv1);
#pragma unroll
      for (int off = 1; off < 16; off <<= 1) tmax = fmaxf(tmax, __shfl_xor(tmax, off));
      float mo = mL[sr];
      float mn = fmaxf(mo, tmax);
      float p0 = __expf(sv0 - mn);
      float p1 = __expf(sv1 - mn);
      float psum = p0 + p1;
#pragma unroll
      for (int off = 1; off < 16; off <<= 1) psum += __shfl_xor(psum, off);
      if (kd == 0) {
        float fsc = __expf(mo - mn);
        mL[sr] = mn;
        lL[sr] = lL[sr] * fsc + psum;
        fL[sr] = fsc;
      }
      Pt[kb + 0][sr] = p0;
      Pt[kb + 1][sr] = p1;
    }

    // ---- write staged next tile to LDS (buffer nb) ----
    if (kt + 1 < NT) {
#pragma unroll
      for (int u = 0; u < 4; ++u) *(float4*)&Vs[nb][vw * 4 + u][lane * 4] = vreg[u];
      if (dopk) {
        pkT[nb][ps_ * 4 + 0][pr_] = pkreg.x;
        pkT[nb][ps_ * 4 + 1][pr_] = pkreg.y;
        pkT[nb][ps_ * 4 + 2][pr_] = pkreg.z;
        pkT[nb][ps_ * 4 + 3][pr_] = pkreg.w;
      }
      if (dokn) {
        kn2s[nb][t * 4 + 0] = knreg.x; khs[nb][t * 4 + 0] = sqrtf(knreg.x + 1e-6f);
        kn2s[nb][t * 4 + 1] = knreg.y; khs[nb][t * 4 + 1] = sqrtf(knreg.y + 1e-6f);
        kn2s[nb][t * 4 + 2] = knreg.z; khs[nb][t * 4 + 2] = sqrtf(knreg.z + 1e-6f);
        kn2s[nb][t * 4 + 3] = knreg.w; khs[nb][t * 4 + 3] = sqrtf(knreg.w + 1e-6f);
      }
    }
    __syncthreads();  // A: Pt + fL ready; next-tile LDS staged

    // ---- PV from buffer cur ----
    {
      const float(*Vc)[256] = Vs[cur];
      float fr0 = fL[rg * 4 + 0], fr1 = fL[rg * 4 + 1];
      float fr2 = fL[rg * 4 + 2], fr3 = fL[rg * 4 + 3];
      acc2[0][0] *= fr0; acc2[0][1] *= fr0;
      acc2[1][0] *= fr1; acc2[1][1] *= fr1;
      acc2[2][0] *= fr2; acc2[2][1] *= fr2;
      acc2[3][0] *= fr3; acc2[3][1] *= fr3;
#pragma unroll
      for (int kk = 0; kk < KT; ++kk) {
        float4 p4 = *(const float4*)&Pt[kk][rg * 4];
        float4 v4 = *(const float4*)&Vc[kk][cg * 4];
        v2f va = {v4.x, v4.y}, vb = {v4.z, v4.w};
        acc2[0][0] += p4.x * va; acc2[0][1] += p4.x * vb;
        acc2[1][0] += p4.y * va; acc2[1][1] += p4.y * vb;
        acc2[2][0] += p4.z * va; acc2[2][1] += p4.z * vb;
        acc2[3][0] += p4.w * va; acc2[3][1] += p4.w * vb;
      }
    }
    __syncthreads();  // B: PV done before Pt/Vs[cur] rewritten
    cur = nb;
  }

#pragma unroll
  for (int rr = 0; rr < 4; ++rr) {
    int r = rg * 4 + rr;
    float linv = 1.f / lL[r];
    float* dst = attn_out + ((size_t)b * S_ + q0 + r) * D_ + h * DK_ + cg * 4;
    float4 o;
    o.x = acc2[rr][0].x * linv;
    o.y = acc2[rr][0].y * linv;
    o.z = acc2[rr][1].x * linv;
    o.w = acc2[rr][1].y * linv;
    *(float4*)dst = o;
  }
}

// ---------------- output projection: C = A @ W^T + bias ----------------
__global__ __launch_bounds__(256) void k_wo(const float* __restrict__ A,
                                            const float* __restrict__ W,
                                            const float* __restrict__ bias,
                                            float* __restrict__ C) {
  __shared__ __align__(16) float As[32][68];
  __shared__ __align__(16) float Bs[32][68];
  int t = threadIdx.x;
  int tx = t & 15, ty = t >> 4;
  int n0 = blockIdx.x * 64;
  int m0 = blockIdx.y * 64;
  v2f acc2[4][2];
#pragma unroll
  for (int i = 0; i < 4; ++i) {
    acc2[i][0] = (v2f){0.f, 0.f};
    acc2[i][1] = (v2f){0.f, 0.f};
  }

  for (int k0 = 0; k0 < D_; k0 += 32) {
#pragma unroll
    for (int u = 0; u < 2; ++u) {
      int idx = t + 256 * u;
      int row = idx >> 3, cf = idx & 7;
      float4 a = *(const float4*)(A + (size_t)(m0 + row) * D_ + k0 + cf * 4);
      As[cf * 4 + 0][row] = a.x; As[cf * 4 + 1][row] = a.y;
      As[cf * 4 + 2][row] = a.z; As[cf * 4 + 3][row] = a.w;
      float4 bb = *(const float4*)(W + (size_t)(n0 + row) * D_ + k0 + cf * 4);
      Bs[cf * 4 + 0][row] = bb.x; Bs[cf * 4 + 1][row] = bb.y;
      Bs[cf * 4 + 2][row] = bb.z; Bs[cf * 4 + 3][row] = bb.w;
    }
    __syncthreads();
#pragma unroll 8
    for (int kk = 0; kk < 32; ++kk) {
      float4 a4 = *(const float4*)&As[kk][ty * 4];
      float4 b4 = *(const float4*)&Bs[kk][tx * 4];
      v2f bv0 = {b4.x, b4.y}, bv1 = {b4.z, b4.w};
      acc2[0][0] += a4.x * bv0; acc2[0][1] += a4.x * bv1;
      acc2[1][0] += a4.y * bv0; acc2[1][1] += a4.y * bv1;
      acc2[2][0] += a4.z * bv0; acc2[2][1] += a4.z * bv1;
      acc2[3][0] += a4.w * bv0; acc2[3][1] += a4.w * bv1;
    }
    __syncthreads();
  }
  float4 b4 = *(const float4*)(bias + n0 + tx * 4);
#pragma unroll
  for (int i = 0; i < 4; ++i) {
    float4 o;
    o.x = acc2[i][0].x + b4.x;
    o.y = acc2[i][0].y + b4.y;
    o.z = acc2[i][1].x + b4.z;
    o.w = acc2[i][1].y + b4.w;
    *(float4*)(C + (size_t)(m0 + ty * 4 + i) * D_ + n0 + tx * 4) = o;
  }
}

extern "C" void kernel_launch(void* const* d_in, const int* in_sizes, int n_in,
                              void* d_out, int out_size, void* d_ws, size_t ws_size,
                              hipStream_t stream) {
  const float* Q_input = (const float*)d_in[0];
  const float* K = (const float*)d_in[1];
  const float* V = (const float*)d_in[2];
  // d_in[3] = T_field: unused by the reference
  const float* Wq_w = (const float*)d_in[4];
  const float* Wq_b = (const float*)d_in[5];
  const float* Wo_w = (const float*)d_in[6];
  const float* Wo_b = (const float*)d_in[7];
  const float* proj_w = (const float*)d_in[8];
  const float* proj_b = (const float*)d_in[9];
  const float* geo_w = (const float*)d_in[10];
  const float* temp = (const float*)d_in[11];

  float* ws = (float*)d_ws;
  float* M = ws;                       // 1024*96      = 98304
  float* cbias = M + 98304;            // 96 (pad 128)
  float* pq = cbias + 128;             // 2*4*2048*16  = 262144
  float* qn2 = pq + 262144;            // 16384
  float* pk = qn2 + 16384;             // 262144
  float* kn2 = pk + 262144;            // 16384
  float* attn = kn2 + 16384;           // 2*2048*1024  = 4194304
  float* out = (float*)d_out;

  k_fuse<<<dim3(384), dim3(256), 0, stream>>>(Wq_w, proj_w, M);
  k_fuse_bias<<<dim3(1), dim3(128), 0, stream>>>(Wq_b, proj_w, proj_b, cbias);
  k_genq<<<dim3(512), dim3(128), 0, stream>>>(Q_input, M, cbias, pq, qn2);
  k_genk<<<dim3(512), dim3(128), 0, stream>>>(K, proj_w, proj_b, pk, kn2);
  k_attn<<<dim3(512), dim3(512), 0, stream>>>(pq, qn2, pk, kn2, V, geo_w, temp, attn);
  k_wo<<<dim3(16, 64), dim3(256), 0, stream>>>(attn, Wo_w, Wo_b, out);
}

// Round 5
// 277.120 us; speedup vs baseline: 2.2974x; 2.2974x over previous
//
#include <hip/hip_runtime.h>
#include <hip/hip_bf16.h>
#include <math.h>

#define B_ 2
#define S_ 2048
#define D_ 1024
#define H_ 4
#define DK_ 256
#define NJ 24
#define NG 96
#define KTA 128
#define NT2 (S_ / KTA)

typedef _Float16 f16;
typedef _Float16 f16x2 __attribute__((ext_vector_type(2)));
typedef _Float16 f16x8 __attribute__((ext_vector_type(8)));
typedef float f32x16 __attribute__((ext_vector_type(16)));

// ---------------- kernel 1: fold Wq into proj ----------------
__global__ __launch_bounds__(256) void k_fuse(const float* __restrict__ Wq_w,
                                              const float* __restrict__ proj_w,
                                              float* __restrict__ M) {
  int tid = blockIdx.x * 256 + threadIdx.x;
  int hj = tid >> 10;
  int d = tid & 1023;
  int h = hj / NJ, j = hj - h * NJ;
  const float* wq = Wq_w + (size_t)(h * DK_) * D_ + d;
  const float* pw = proj_w + j * DK_;
  float acc = 0.f;
#pragma unroll 8
  for (int k = 0; k < DK_; ++k) acc += wq[(size_t)k * D_] * pw[k];
  M[(size_t)d * NG + hj] = acc;
}

__global__ void k_fuse_bias(const float* __restrict__ Wq_b,
                            const float* __restrict__ proj_w,
                            const float* __restrict__ proj_b,
                            float* __restrict__ cbias) {
  int hj = threadIdx.x;
  if (hj < NG) {
    int h = hj / NJ, j = hj - h * NJ;
    float acc = proj_b[j];
    for (int k = 0; k < DK_; ++k) acc += Wq_b[h * DK_ + k] * proj_w[j * DK_ + k];
    cbias[hj] = acc;
  }
}

// ---------------- V transpose + f16: Vt[bh][vc 256][s 2048] ----------------
__global__ __launch_bounds__(256) void k_vt(const float* __restrict__ V,
                                            f16* __restrict__ Vt) {
  __shared__ f16 tile[64][72];
  int t = threadIdx.x;
  int s0 = blockIdx.x * 64, c0 = blockIdx.y * 64;
  int bh = blockIdx.z;
  int b = bh >> 2, h = bh & 3;
  const float* src = V + (size_t)b * S_ * D_ + h * DK_ + c0;
#pragma unroll
  for (int u = 0; u < 4; ++u) {
    int row = (t >> 4) + 16 * u;
    int c4 = (t & 15) * 4;
    float4 v = *(const float4*)(src + (size_t)(s0 + row) * D_ + c4);
    tile[c4 + 0][row] = (f16)v.x;
    tile[c4 + 1][row] = (f16)v.y;
    tile[c4 + 2][row] = (f16)v.z;
    tile[c4 + 3][row] = (f16)v.w;
  }
  __syncthreads();
  int vc = t & 63, seg = t >> 6;
  f16* dst = Vt + ((size_t)bh * DK_ + c0 + vc) * S_ + s0 + seg * 16;
  *(f16x8*)dst = *(f16x8*)&tile[vc][seg * 16];
  *(f16x8*)(dst + 8) = *(f16x8*)&tile[vc][seg * 16 + 8];
}

// ---------------- psi from gen rows (8 rows per block), f16 out ----------------
__device__ __forceinline__ void psi_store(const float (*genL)[NG], int t, int g0,
                                          f16* __restrict__ po,
                                          float* __restrict__ n2o) {
  if (t < 64) {
    int h = t >> 4, ii = t & 15, j = ii & 7;
#pragma unroll 2
    for (int r = 0; r < 8; ++r) {
      int g = g0 + r;
      int b = g >> 11, s = g & (S_ - 1);
      const float* gl = genL[r] + h * NJ;
      float A = gl[j], Bg = gl[8 + j];
      float Th = fminf(fmaxf(gl[16 + j], -8.f), 8.f);
      float val = (ii < 8) ? (A * expf(Th) + Bg * cosf(Th)) : (Bg * sinf(Th));
      size_t base = (size_t)(b * H_ + h) * S_ + s;
      po[base * 16 + ii] = (f16)val;
      float sq = val * val;
#pragma unroll
      for (int off = 1; off < 16; off <<= 1) sq += __shfl_xor(sq, off);
      if (ii == 0) n2o[base] = sq;
    }
  }
}

// ---------------- gen_q = Q_input @ M + cbias, then psi ----------------
__global__ __launch_bounds__(128) void k_genq(const float* __restrict__ Q,
                                              const float* __restrict__ M,
                                              const float* __restrict__ cbias,
                                              f16* __restrict__ pqF,
                                              float* __restrict__ qn2) {
  __shared__ __align__(16) float qlds[8][D_];
  __shared__ float genL[8][NG];
  int t = threadIdx.x;
  int g0 = blockIdx.x * 8;
  {
    const float4* src = (const float4*)(Q + (size_t)g0 * D_);
    float4* dst = (float4*)&qlds[0][0];
#pragma unroll
    for (int u = 0; u < 16; ++u) dst[t + 128 * u] = src[t + 128 * u];
  }
  __syncthreads();
  if (t < NG) {
    float cb = cbias[t];
    float acc[8];
#pragma unroll
    for (int r = 0; r < 8; ++r) acc[r] = cb;
    const float* Mp = M + t;
#pragma unroll 2
    for (int d0 = 0; d0 < D_; d0 += 4) {
      float m0 = Mp[(size_t)(d0 + 0) * NG];
      float m1 = Mp[(size_t)(d0 + 1) * NG];
      float m2 = Mp[(size_t)(d0 + 2) * NG];
      float m3 = Mp[(size_t)(d0 + 3) * NG];
#pragma unroll
      for (int r = 0; r < 8; ++r) {
        float4 q4 = *(const float4*)&qlds[r][d0];
        acc[r] += q4.x * m0 + q4.y * m1 + q4.z * m2 + q4.w * m3;
      }
    }
#pragma unroll
    for (int r = 0; r < 8; ++r) genL[r][t] = acc[r];
  }
  __syncthreads();
  psi_store(genL, t, g0, pqF, qn2);
}

// ---------------- gen_k = K_head @ proj_w.T + proj_b, then psi ----------------
__global__ __launch_bounds__(128) void k_genk(const float* __restrict__ Kin,
                                              const float* __restrict__ proj_w,
                                              const float* __restrict__ proj_b,
                                              f16* __restrict__ pkF,
                                              float* __restrict__ kn2) {
  __shared__ __align__(16) float klds[8][D_];
  __shared__ float genL[8][NG];
  __shared__ float pwT[DK_][NJ];
  int t = threadIdx.x;
  int g0 = blockIdx.x * 8;
  {
    const float4* src = (const float4*)(Kin + (size_t)g0 * D_);
    float4* dst = (float4*)&klds[0][0];
#pragma unroll
    for (int u = 0; u < 16; ++u) dst[t + 128 * u] = src[t + 128 * u];
  }
  for (int idx = t; idx < NJ * DK_; idx += 128) {
    int j = idx >> 8, c = idx & 255;
    pwT[c][j] = proj_w[idx];
  }
  __syncthreads();
  if (t < NG) {
    int h = t / NJ, j = t - h * NJ;
    float pb = proj_b[j];
    float acc[8];
#pragma unroll
    for (int r = 0; r < 8; ++r) acc[r] = pb;
#pragma unroll 2
    for (int c0 = 0; c0 < DK_; c0 += 4) {
      float w0 = pwT[c0][j], w1 = pwT[c0 + 1][j];
      float w2 = pwT[c0 + 2][j], w3 = pwT[c0 + 3][j];
#pragma unroll
      for (int r = 0; r < 8; ++r) {
        float4 k4 = *(const float4*)&klds[r][h * DK_ + c0];
        acc[r] += k4.x * w0 + k4.y * w1 + k4.z * w2 + k4.w * w3;
      }
    }
#pragma unroll
    for (int r = 0; r < 8; ++r) genL[r][t] = acc[r];
  }
  __syncthreads();
  psi_store(genL, t, g0, pkF, kn2);
}

// ---------------- MFMA flash geometric attention ----------------
// 8 waves, QT=32, KT=128. Scores swapped: A=[psi_k;J psi_k] (M=32), B=psi_q (N=32).
// C row=(r&3)+8*(r>>2)+4*lh = k-entity, col=lane&31=q. PV: A=P(32q x 16k), B=Vt.
__global__ __launch_bounds__(512, 4) void k_attn(
    const f16* __restrict__ pqF, const float* __restrict__ qn2,
    const f16* __restrict__ pkF, const float* __restrict__ kn2,
    const f16* __restrict__ Vt, const float* __restrict__ geo_w,
    const float* __restrict__ temp, f16* __restrict__ attn_out) {
  __shared__ float kn2s[KTA], khs[KTA];
  __shared__ float mPart[8][32], sPart[8][32];
  __shared__ float mbuf[2][32], fL[32], lfin[32];
  __shared__ __align__(16) f16 Plds[32][136];  // 272B rows: b128-aligned

  const int t = threadIdx.x;
  const int w = t >> 6;
  const int lane = t & 63;
  const int q_ = lane & 31;
  const int lh = lane >> 5;

  const int bid = blockIdx.x;
  const int bh = bid & 7, qt = bid >> 3;
  const int h = bh & 3, b = bh >> 2;
  const int q0 = qt * 32;

  const size_t bhS = (size_t)bh * S_;
  const f16* pkb = pkF + bhS * 16;
  const float* kn2b = kn2 + bhS;

  const float scale = 0.25f / temp[0];
  const float g0s = geo_w[0] * scale, g1s = geo_w[1] * scale, g2s = geo_w[2] * scale;
  const float g3s = geo_w[3] * scale;

  // B-frag psi_q (persistent) + per-lane q stats
  const f16x8 bq = *(const f16x8*)(pqF + (bhS + q0 + q_) * 16 + lh * 8);
  const float qn2q = qn2[bhS + q0 + q_];
  const float qh3 = sqrtf(qn2q + 1e-6f) * g3s;

  if (t < KTA) { float kv = kn2b[t]; kn2s[t] = kv; khs[t] = sqrtf(kv + 1e-6f); }
  if (t < 32) mbuf[0][t] = -INFINITY;
  float lreg = 0.f;
  f32x16 acc{};
  const f32x16 zacc{};
  __syncthreads();

  for (int kt = 0; kt < NT2; ++kt) {
    const int k0 = kt * KTA;
    const int kg = k0 + w * 16;

    // ---- scores ----
    const f16* ap = pkb + (size_t)(kg + (q_ & 15)) * 16 + ((q_ < 16) ? lh * 8 : (1 - lh) * 8);
    f16x8 af = *(const f16x8*)ap;
    if (q_ >= 16 && lh == 1) af = -af;
    f32x16 sc = __builtin_amdgcn_mfma_f32_32x32x16_f16(af, bq, zacc, 0, 0, 0);

    float sv[8];
    float tmax = -INFINITY;
#pragma unroll
    for (int r = 0; r < 8; ++r) {
      const int kk = (r & 3) + 8 * (r >> 2) + 4 * lh;
      float tn = sc[r], sp = sc[r + 8];
      float wr = qn2q * kn2s[w * 16 + kk] - tn * tn - sp * sp;
      float wg = sqrtf(fmaxf(wr, 0.f) + 1e-6f);
      sv[r] = g0s * wg + g1s * tn + g2s * sp + qh3 * khs[w * 16 + kk];
      tmax = fmaxf(tmax, sv[r]);
    }
    tmax = fmaxf(tmax, __shfl_xor(tmax, 32));
    if (lh == 0) mPart[w][q_] = tmax;
    __syncthreads();  // bar1

    float mold = mbuf[kt & 1][q_];
    float mn = mold;
#pragma unroll
    for (int i = 0; i < 8; ++i) mn = fmaxf(mn, mPart[i][q_]);
    // stage next-tile kn2 (safe post-bar1: this tile's reads are done)
    if (t < KTA && kt + 1 < NT2) {
      float kv = kn2b[k0 + KTA + t];
      kn2s[t] = kv;
      khs[t] = sqrtf(kv + 1e-6f);
    }
    float pv[8];
    float ps = 0.f;
#pragma unroll
    for (int r = 0; r < 8; ++r) { pv[r] = __expf(sv[r] - mn); ps += pv[r]; }
    ps += __shfl_xor(ps, 32);
    if (lh == 0) sPart[w][q_] = ps;
    if (w == 0 && lh == 0) {
      mbuf[(kt & 1) ^ 1][q_] = mn;
      fL[q_] = __expf(mold - mn);
    }
    {
      f16x2 p01 = {(f16)pv[0], (f16)pv[1]};
      f16x2 p23 = {(f16)pv[2], (f16)pv[3]};
      f16x2 p45 = {(f16)pv[4], (f16)pv[5]};
      f16x2 p67 = {(f16)pv[6], (f16)pv[7]};
      const int kb = w * 16 + 4 * lh;
      *(f16x2*)&Plds[q_][kb + 0] = p01;
      *(f16x2*)&Plds[q_][kb + 2] = p23;
      *(f16x2*)&Plds[q_][kb + 8] = p45;
      *(f16x2*)&Plds[q_][kb + 10] = p67;
    }
    __syncthreads();  // bar2

    // ---- PV ----
#pragma unroll
    for (int r = 0; r < 16; ++r) acc[r] *= fL[(r & 3) + 8 * (r >> 2) + 4 * lh];
    if (w == 0 && lh == 0) {
      float s8 = 0.f;
#pragma unroll
      for (int i = 0; i < 8; ++i) s8 += sPart[i][q_];
      lreg = lreg * fL[q_] + s8;
    }
    const f16* vb = Vt + ((size_t)bh * DK_ + w * 32 + q_) * S_ + k0;
#pragma unroll
    for (int ks = 0; ks < 8; ++ks) {
      f16x8 pa = *(const f16x8*)&Plds[q_][ks * 16 + lh * 8];
      f16x8 bv = *(const f16x8*)(vb + ks * 16 + lh * 8);
      acc = __builtin_amdgcn_mfma_f32_32x32x16_f16(pa, bv, acc, 0, 0, 0);
    }
  }

  if (w == 0 && lh == 0) lfin[q_] = 1.f / lreg;
  __syncthreads();
  const size_t obase = ((size_t)b * S_ + q0) * D_ + h * DK_ + w * 32 + q_;
#pragma unroll
  for (int r = 0; r < 16; ++r) {
    const int row = (r & 3) + 8 * (r >> 2) + 4 * lh;
    attn_out[obase + (size_t)row * D_] = (f16)(acc[r] * lfin[row]);
  }
}

// ---------------- output projection via f16 MFMA ----------------
__global__ __launch_bounds__(256, 4) void k_wo(const f16* __restrict__ A,
                                               const float* __restrict__ W,
                                               const float* __restrict__ bias,
                                               float* __restrict__ C) {
  const int t = threadIdx.x;
  const int w = t >> 6;
  const int lane = t & 63;
  const int l31 = lane & 31, lh = lane >> 5;
  const int m0 = blockIdx.y * 64 + (w & 1) * 32;
  const int n0 = blockIdx.x * 64 + (w >> 1) * 32;
  f32x16 acc{};
  const f16* ap = A + (size_t)(m0 + l31) * D_ + lh * 8;
  const float* wp = W + (size_t)(n0 + l31) * D_ + lh * 8;
#pragma unroll 2
  for (int k0 = 0; k0 < D_; k0 += 16) {
    f16x8 af = *(const f16x8*)(ap + k0);
    float4 w0 = *(const float4*)(wp + k0);
    float4 w1 = *(const float4*)(wp + k0 + 4);
    f16x8 bf;
    bf[0] = (f16)w0.x; bf[1] = (f16)w0.y; bf[2] = (f16)w0.z; bf[3] = (f16)w0.w;
    bf[4] = (f16)w1.x; bf[5] = (f16)w1.y; bf[6] = (f16)w1.z; bf[7] = (f16)w1.w;
    acc = __builtin_amdgcn_mfma_f32_32x32x16_f16(af, bf, acc, 0, 0, 0);
  }
  const float bv = bias[n0 + l31];
#pragma unroll
  for (int r = 0; r < 16; ++r) {
    const int row = (r & 3) + 8 * (r >> 2) + 4 * lh;
    C[(size_t)(m0 + row) * D_ + n0 + l31] = acc[r] + bv;
  }
}

extern "C" void kernel_launch(void* const* d_in, const int* in_sizes, int n_in,
                              void* d_out, int out_size, void* d_ws, size_t ws_size,
                              hipStream_t stream) {
  const float* Q_input = (const float*)d_in[0];
  const float* K = (const float*)d_in[1];
  const float* V = (const float*)d_in[2];
  const float* Wq_w = (const float*)d_in[4];
  const float* Wq_b = (const float*)d_in[5];
  const float* Wo_w = (const float*)d_in[6];
  const float* Wo_b = (const float*)d_in[7];
  const float* proj_w = (const float*)d_in[8];
  const float* proj_b = (const float*)d_in[9];
  const float* geo_w = (const float*)d_in[10];
  const float* temp = (const float*)d_in[11];

  float* ws = (float*)d_ws;
  float* M = ws;                          // 98304 f32
  float* cbias = M + 98304;               // 128
  float* qn2 = cbias + 128;               // 16384
  float* kn2 = qn2 + 16384;               // 16384
  f16* pqF = (f16*)(kn2 + 16384);         // 262144 f16 (131072 f32-units)
  f16* pkF = (f16*)(kn2 + 16384 + 131072);
  f16* Vt = (f16*)(kn2 + 16384 + 262144);       // 4194304 f16
  f16* attnF = (f16*)(kn2 + 16384 + 262144 + 2097152);  // 4194304 f16
  float* out = (float*)d_out;

  k_fuse<<<dim3(384), dim3(256), 0, stream>>>(Wq_w, proj_w, M);
  k_fuse_bias<<<dim3(1), dim3(128), 0, stream>>>(Wq_b, proj_w, proj_b, cbias);
  k_vt<<<dim3(32, 4, 8), dim3(256), 0, stream>>>(V, Vt);
  k_genq<<<dim3(512), dim3(128), 0, stream>>>(Q_input, M, cbias, pqF, qn2);
  k_genk<<<dim3(512), dim3(128), 0, stream>>>(K, proj_w, proj_b, pkF, kn2);
  k_attn<<<dim3(512), dim3(512), 0, stream>>>(pqF, qn2, pkF, kn2, Vt, geo_w, temp, attnF);
  k_wo<<<dim3(16, 64), dim3(256), 0, stream>>>(attnF, Wo_w, Wo_b, out);
}

// Round 6
// 215.327 us; speedup vs baseline: 2.9567x; 1.2870x over previous
//
#include <hip/hip_runtime.h>
#include <hip/hip_bf16.h>
#include <math.h>

#define B_ 2
#define S_ 2048
#define D_ 1024
#define H_ 4
#define DK_ 256
#define NJ 24
#define NG 96
#define KTA 128
#define NT2 (S_ / KTA)

typedef _Float16 f16;
typedef _Float16 f16x2 __attribute__((ext_vector_type(2)));
typedef _Float16 f16x8 __attribute__((ext_vector_type(8)));
typedef float f32x16 __attribute__((ext_vector_type(16)));

// ---------------- kernel 1: fold Wq into proj ----------------
__global__ __launch_bounds__(256) void k_fuse(const float* __restrict__ Wq_w,
                                              const float* __restrict__ proj_w,
                                              float* __restrict__ M) {
  int tid = blockIdx.x * 256 + threadIdx.x;
  int hj = tid >> 10;
  int d = tid & 1023;
  int h = hj / NJ, j = hj - h * NJ;
  const float* wq = Wq_w + (size_t)(h * DK_) * D_ + d;
  const float* pw = proj_w + j * DK_;
  float acc = 0.f;
#pragma unroll 8
  for (int k = 0; k < DK_; ++k) acc += wq[(size_t)k * D_] * pw[k];
  M[(size_t)d * NG + hj] = acc;
}

__global__ void k_fuse_bias(const float* __restrict__ Wq_b,
                            const float* __restrict__ proj_w,
                            const float* __restrict__ proj_b,
                            float* __restrict__ cbias) {
  int hj = threadIdx.x;
  if (hj < NG) {
    int h = hj / NJ, j = hj - h * NJ;
    float acc = proj_b[j];
    for (int k = 0; k < DK_; ++k) acc += Wq_b[h * DK_ + k] * proj_w[j * DK_ + k];
    cbias[hj] = acc;
  }
}

// ---------------- W -> f16 convert ----------------
__global__ __launch_bounds__(256) void k_wcvt(const float* __restrict__ W,
                                              f16* __restrict__ Wt) {
  int i = (blockIdx.x * 256 + threadIdx.x) * 8;
  float4 a = *(const float4*)(W + i);
  float4 b = *(const float4*)(W + i + 4);
  f16x8 o = {(f16)a.x, (f16)a.y, (f16)a.z, (f16)a.w,
             (f16)b.x, (f16)b.y, (f16)b.z, (f16)b.w};
  *(f16x8*)(Wt + i) = o;
}

// ---------------- V transpose + f16: Vt[bh][vc 256][s 2048] ----------------
__global__ __launch_bounds__(256) void k_vt(const float* __restrict__ V,
                                            f16* __restrict__ Vt) {
  __shared__ f16 tile[64][72];
  int t = threadIdx.x;
  int s0 = blockIdx.x * 64, c0 = blockIdx.y * 64;
  int bh = blockIdx.z;
  int b = bh >> 2, h = bh & 3;
  const float* src = V + (size_t)b * S_ * D_ + h * DK_ + c0;
#pragma unroll
  for (int u = 0; u < 4; ++u) {
    int row = (t >> 4) + 16 * u;
    int c4 = (t & 15) * 4;
    float4 v = *(const float4*)(src + (size_t)(s0 + row) * D_ + c4);
    tile[c4 + 0][row] = (f16)v.x;
    tile[c4 + 1][row] = (f16)v.y;
    tile[c4 + 2][row] = (f16)v.z;
    tile[c4 + 3][row] = (f16)v.w;
  }
  __syncthreads();
  int vc = t & 63, seg = t >> 6;
  f16* dst = Vt + ((size_t)bh * DK_ + c0 + vc) * S_ + s0 + seg * 16;
  *(f16x8*)dst = *(f16x8*)&tile[vc][seg * 16];
  *(f16x8*)(dst + 8) = *(f16x8*)&tile[vc][seg * 16 + 8];
}

// ---------------- psi from gen rows (8 rows per block), f16 out ----------------
__device__ __forceinline__ void psi_store(const float (*genL)[NG], int t, int g0,
                                          f16* __restrict__ po,
                                          float* __restrict__ n2o) {
  if (t < 64) {
    int h = t >> 4, ii = t & 15, j = ii & 7;
#pragma unroll 2
    for (int r = 0; r < 8; ++r) {
      int g = g0 + r;
      int b = g >> 11, s = g & (S_ - 1);
      const float* gl = genL[r] + h * NJ;
      float A = gl[j], Bg = gl[8 + j];
      float Th = fminf(fmaxf(gl[16 + j], -8.f), 8.f);
      float val = (ii < 8) ? (A * expf(Th) + Bg * cosf(Th)) : (Bg * sinf(Th));
      size_t base = (size_t)(b * H_ + h) * S_ + s;
      po[base * 16 + ii] = (f16)val;
      float sq = val * val;
#pragma unroll
      for (int off = 1; off < 16; off <<= 1) sq += __shfl_xor(sq, off);
      if (ii == 0) n2o[base] = sq;
    }
  }
}

// ---------------- gen_q = Q_input @ M + cbias, then psi ----------------
__global__ __launch_bounds__(128) void k_genq(const float* __restrict__ Q,
                                              const float* __restrict__ M,
                                              const float* __restrict__ cbias,
                                              f16* __restrict__ pqF,
                                              float* __restrict__ qn2) {
  __shared__ __align__(16) float qlds[8][D_];
  __shared__ float genL[8][NG];
  int t = threadIdx.x;
  int g0 = blockIdx.x * 8;
  {
    const float4* src = (const float4*)(Q + (size_t)g0 * D_);
    float4* dst = (float4*)&qlds[0][0];
#pragma unroll
    for (int u = 0; u < 16; ++u) dst[t + 128 * u] = src[t + 128 * u];
  }
  __syncthreads();
  if (t < NG) {
    float cb = cbias[t];
    float acc[8];
#pragma unroll
    for (int r = 0; r < 8; ++r) acc[r] = cb;
    const float* Mp = M + t;
#pragma unroll 2
    for (int d0 = 0; d0 < D_; d0 += 4) {
      float m0 = Mp[(size_t)(d0 + 0) * NG];
      float m1 = Mp[(size_t)(d0 + 1) * NG];
      float m2 = Mp[(size_t)(d0 + 2) * NG];
      float m3 = Mp[(size_t)(d0 + 3) * NG];
#pragma unroll
      for (int r = 0; r < 8; ++r) {
        float4 q4 = *(const float4*)&qlds[r][d0];
        acc[r] += q4.x * m0 + q4.y * m1 + q4.z * m2 + q4.w * m3;
      }
    }
#pragma unroll
    for (int r = 0; r < 8; ++r) genL[r][t] = acc[r];
  }
  __syncthreads();
  psi_store(genL, t, g0, pqF, qn2);
}

// ---------------- gen_k = K_head @ proj_w.T + proj_b, then psi ----------------
__global__ __launch_bounds__(128) void k_genk(const float* __restrict__ Kin,
                                              const float* __restrict__ proj_w,
                                              const float* __restrict__ proj_b,
                                              f16* __restrict__ pkF,
                                              float* __restrict__ kn2) {
  __shared__ __align__(16) float klds[8][D_];
  __shared__ float genL[8][NG];
  __shared__ float pwT[DK_][NJ];
  int t = threadIdx.x;
  int g0 = blockIdx.x * 8;
  {
    const float4* src = (const float4*)(Kin + (size_t)g0 * D_);
    float4* dst = (float4*)&klds[0][0];
#pragma unroll
    for (int u = 0; u < 16; ++u) dst[t + 128 * u] = src[t + 128 * u];
  }
  for (int idx = t; idx < NJ * DK_; idx += 128) {
    int j = idx >> 8, c = idx & 255;
    pwT[c][j] = proj_w[idx];
  }
  __syncthreads();
  if (t < NG) {
    int h = t / NJ, j = t - h * NJ;
    float pb = proj_b[j];
    float acc[8];
#pragma unroll
    for (int r = 0; r < 8; ++r) acc[r] = pb;
#pragma unroll 2
    for (int c0 = 0; c0 < DK_; c0 += 4) {
      float w0 = pwT[c0][j], w1 = pwT[c0 + 1][j];
      float w2 = pwT[c0 + 2][j], w3 = pwT[c0 + 3][j];
#pragma unroll
      for (int r = 0; r < 8; ++r) {
        float4 k4 = *(const float4*)&klds[r][h * DK_ + c0];
        acc[r] += k4.x * w0 + k4.y * w1 + k4.z * w2 + k4.w * w3;
      }
    }
#pragma unroll
    for (int r = 0; r < 8; ++r) genL[r][t] = acc[r];
  }
  __syncthreads();
  psi_store(genL, t, g0, pkF, kn2);
}

// ---------------- MFMA flash geometric attention ----------------
__global__ __launch_bounds__(512, 4) void k_attn(
    const f16* __restrict__ pqF, const float* __restrict__ qn2,
    const f16* __restrict__ pkF, const float* __restrict__ kn2,
    const f16* __restrict__ Vt, const float* __restrict__ geo_w,
    const float* __restrict__ temp, f16* __restrict__ attn_out) {
  __shared__ float kn2s[KTA], khs[KTA];
  __shared__ float mPart[8][32], sPart[8][32];
  __shared__ float mbuf[2][32], fL[32], lfin[32];
  __shared__ __align__(16) f16 Plds[32][136];  // 272B rows: b128-aligned

  const int t = threadIdx.x;
  const int w = t >> 6;
  const int lane = t & 63;
  const int q_ = lane & 31;
  const int lh = lane >> 5;

  const int bid = blockIdx.x;
  const int bh = bid & 7, qt = bid >> 3;
  const int h = bh & 3, b = bh >> 2;
  const int q0 = qt * 32;

  const size_t bhS = (size_t)bh * S_;
  const f16* pkb = pkF + bhS * 16;
  const float* kn2b = kn2 + bhS;

  const float scale = 0.25f / temp[0];
  const float g0s = geo_w[0] * scale, g1s = geo_w[1] * scale, g2s = geo_w[2] * scale;
  const float g3s = geo_w[3] * scale;

  const f16x8 bq = *(const f16x8*)(pqF + (bhS + q0 + q_) * 16 + lh * 8);
  const float qn2q = qn2[bhS + q0 + q_];
  const float qh3 = sqrtf(qn2q + 1e-6f) * g3s;

  if (t < KTA) { float kv = kn2b[t]; kn2s[t] = kv; khs[t] = sqrtf(kv + 1e-6f); }
  if (t < 32) mbuf[0][t] = -INFINITY;
  float lreg = 0.f;
  f32x16 acc{};
  const f32x16 zacc{};
  __syncthreads();

  for (int kt = 0; kt < NT2; ++kt) {
    const int k0 = kt * KTA;
    const int kg = k0 + w * 16;

    // ---- scores ----
    const f16* ap = pkb + (size_t)(kg + (q_ & 15)) * 16 + ((q_ < 16) ? lh * 8 : (1 - lh) * 8);
    f16x8 af = *(const f16x8*)ap;
    if (q_ >= 16 && lh == 1) af = -af;
    f32x16 sc = __builtin_amdgcn_mfma_f32_32x32x16_f16(af, bq, zacc, 0, 0, 0);

    float sv[8];
    float tmax = -INFINITY;
#pragma unroll
    for (int r = 0; r < 8; ++r) {
      const int kk = (r & 3) + 8 * (r >> 2) + 4 * lh;
      float tn = sc[r], sp = sc[r + 8];
      float wr = qn2q * kn2s[w * 16 + kk] - tn * tn - sp * sp;
      float wg = sqrtf(fmaxf(wr, 0.f) + 1e-6f);
      sv[r] = g0s * wg + g1s * tn + g2s * sp + qh3 * khs[w * 16 + kk];
      tmax = fmaxf(tmax, sv[r]);
    }
    tmax = fmaxf(tmax, __shfl_xor(tmax, 32));
    if (lh == 0) mPart[w][q_] = tmax;
    __syncthreads();  // bar1

    float mold = mbuf[kt & 1][q_];
    float mn = mold;
#pragma unroll
    for (int i = 0; i < 8; ++i) mn = fmaxf(mn, mPart[i][q_]);
    if (t < KTA && kt + 1 < NT2) {
      float kv = kn2b[k0 + KTA + t];
      kn2s[t] = kv;
      khs[t] = sqrtf(kv + 1e-6f);
    }
    float pv[8];
    float ps = 0.f;
#pragma unroll
    for (int r = 0; r < 8; ++r) { pv[r] = __expf(sv[r] - mn); ps += pv[r]; }
    ps += __shfl_xor(ps, 32);
    if (lh == 0) sPart[w][q_] = ps;
    if (w == 0 && lh == 0) {
      mbuf[(kt & 1) ^ 1][q_] = mn;
      fL[q_] = __expf(mold - mn);
    }
    {
      f16x2 p01 = {(f16)pv[0], (f16)pv[1]};
      f16x2 p23 = {(f16)pv[2], (f16)pv[3]};
      f16x2 p45 = {(f16)pv[4], (f16)pv[5]};
      f16x2 p67 = {(f16)pv[6], (f16)pv[7]};
      const int kb = w * 16 + 4 * lh;
      *(f16x2*)&Plds[q_][kb + 0] = p01;
      *(f16x2*)&Plds[q_][kb + 2] = p23;
      *(f16x2*)&Plds[q_][kb + 8] = p45;
      *(f16x2*)&Plds[q_][kb + 10] = p67;
    }
    __syncthreads();  // bar2

    // ---- PV ----
#pragma unroll
    for (int r = 0; r < 16; ++r) acc[r] *= fL[(r & 3) + 8 * (r >> 2) + 4 * lh];
    if (w == 0 && lh == 0) {
      float s8 = 0.f;
#pragma unroll
      for (int i = 0; i < 8; ++i) s8 += sPart[i][q_];
      lreg = lreg * fL[q_] + s8;
    }
    const f16* vb = Vt + ((size_t)bh * DK_ + w * 32 + q_) * S_ + k0;
#pragma unroll
    for (int ks = 0; ks < 8; ++ks) {
      f16x8 pa = *(const f16x8*)&Plds[q_][ks * 16 + lh * 8];
      f16x8 bv = *(const f16x8*)(vb + ks * 16 + lh * 8);
      acc = __builtin_amdgcn_mfma_f32_32x32x16_f16(pa, bv, acc, 0, 0, 0);
    }
  }

  if (w == 0 && lh == 0) lfin[q_] = 1.f / lreg;
  __syncthreads();
  const size_t obase = ((size_t)b * S_ + q0) * D_ + h * DK_ + w * 32 + q_;
#pragma unroll
  for (int r = 0; r < 16; ++r) {
    const int row = (r & 3) + 8 * (r >> 2) + 4 * lh;
    attn_out[obase + (size_t)row * D_] = (f16)(acc[r] * lfin[row]);
  }
}

// ---------------- output projection: LDS-staged f16 MFMA GEMM ----------------
// 128x128 tile, BK=64, 256 thr = 4 waves (2x2 of 64x64).
// LDS packed in MFMA-fragment subtile order: subtile = 32 rows x 16 k = 1024B,
// element (r,k) at ((k>>3)*32 + r)*16 + (k&7)*2 -> all ds ops wave-linear.
__global__ __launch_bounds__(256, 1) void k_wo(const f16* __restrict__ A,
                                               const f16* __restrict__ Wt,
                                               const float* __restrict__ bias,
                                               float* __restrict__ C) {
  __shared__ __align__(16) f16 Abuf[2][128 * 64];
  __shared__ __align__(16) f16 Bbuf[2][128 * 64];
  const int t = threadIdx.x;
  const int w = t >> 6, lane = t & 63;
  const int wr = w >> 1, wc = w & 1;
  const int brow = blockIdx.y * 128, bcol = blockIdx.x * 128;

  // staging: chunk c = t + 256u; sub=c>>6 (m2*4+kk); l6=c&63;
  // r = m2*32+(l6&31); k = kk*16+(l6>>5)*8
  int srow[4], skof[4];
#pragma unroll
  for (int u = 0; u < 4; ++u) {
    int c = t + 256 * u;
    int sub = c >> 6, l6 = c & 63;
    srow[u] = (sub >> 2) * 32 + (l6 & 31);
    skof[u] = (sub & 3) * 16 + (l6 >> 5) * 8;
  }

  uint4 ra0, ra1, ra2, ra3, rb0, rb1, rb2, rb3;
#define LOAD_TILE(K0)                                                        \
  {                                                                          \
    ra0 = *(const uint4*)(A + (size_t)(brow + srow[0]) * D_ + (K0) + skof[0]); \
    ra1 = *(const uint4*)(A + (size_t)(brow + srow[1]) * D_ + (K0) + skof[1]); \
    ra2 = *(const uint4*)(A + (size_t)(brow + srow[2]) * D_ + (K0) + skof[2]); \
    ra3 = *(const uint4*)(A + (size_t)(brow + srow[3]) * D_ + (K0) + skof[3]); \
    rb0 = *(const uint4*)(Wt + (size_t)(bcol + srow[0]) * D_ + (K0) + skof[0]); \
    rb1 = *(const uint4*)(Wt + (size_t)(bcol + srow[1]) * D_ + (K0) + skof[1]); \
    rb2 = *(const uint4*)(Wt + (size_t)(bcol + srow[2]) * D_ + (K0) + skof[2]); \
    rb3 = *(const uint4*)(Wt + (size_t)(bcol + srow[3]) * D_ + (K0) + skof[3]); \
  }
#define WRITE_TILE(BUF)                                       \
  {                                                           \
    *(uint4*)&Abuf[BUF][(t + 0) * 8] = ra0;                   \
    *(uint4*)&Abuf[BUF][(t + 256) * 8] = ra1;                 \
    *(uint4*)&Abuf[BUF][(t + 512) * 8] = ra2;                 \
    *(uint4*)&Abuf[BUF][(t + 768) * 8] = ra3;                 \
    *(uint4*)&Bbuf[BUF][(t + 0) * 8] = rb0;                   \
    *(uint4*)&Bbuf[BUF][(t + 256) * 8] = rb1;                 \
    *(uint4*)&Bbuf[BUF][(t + 512) * 8] = rb2;                 \
    *(uint4*)&Bbuf[BUF][(t + 768) * 8] = rb3;                 \
  }

  f32x16 acc00{}, acc01{}, acc10{}, acc11{};

  LOAD_TILE(0);
  WRITE_TILE(0);
  LOAD_TILE(64);
  __syncthreads();

  int cur = 0;
  for (int kt = 0; kt < 16; ++kt) {
    // compute from buf[cur]
    const int am0 = (wr * 2 + 0) * 4, am1 = (wr * 2 + 1) * 4;
    const int bn0 = (wc * 2 + 0) * 4, bn1 = (wc * 2 + 1) * 4;
#pragma unroll
    for (int kk = 0; kk < 4; ++kk) {
      f16x8 a0 = *(const f16x8*)&Abuf[cur][(am0 + kk) * 512 + lane * 8];
      f16x8 a1 = *(const f16x8*)&Abuf[cur][(am1 + kk) * 512 + lane * 8];
      f16x8 b0 = *(const f16x8*)&Bbuf[cur][(bn0 + kk) * 512 + lane * 8];
      f16x8 b1 = *(const f16x8*)&Bbuf[cur][(bn1 + kk) * 512 + lane * 8];
      acc00 = __builtin_amdgcn_mfma_f32_32x32x16_f16(a0, b0, acc00, 0, 0, 0);
      acc01 = __builtin_amdgcn_mfma_f32_32x32x16_f16(a0, b1, acc01, 0, 0, 0);
      acc10 = __builtin_amdgcn_mfma_f32_32x32x16_f16(a1, b0, acc10, 0, 0, 0);
      acc11 = __builtin_amdgcn_mfma_f32_32x32x16_f16(a1, b1, acc11, 0, 0, 0);
    }
    if (kt + 1 < 16) {
      WRITE_TILE(cur ^ 1);
      if (kt + 2 < 16) LOAD_TILE((kt + 2) * 64);
    }
    __syncthreads();
    cur ^= 1;
  }

  const int l31 = lane & 31, lh = lane >> 5;
  const float bv0 = bias[bcol + (wc * 2 + 0) * 32 + l31];
  const float bv1 = bias[bcol + (wc * 2 + 1) * 32 + l31];
#pragma unroll
  for (int r = 0; r < 16; ++r) {
    const int row = (r & 3) + 8 * (r >> 2) + 4 * lh;
    const size_t m0r = (size_t)(brow + (wr * 2 + 0) * 32 + row) * D_;
    const size_t m1r = (size_t)(brow + (wr * 2 + 1) * 32 + row) * D_;
    C[m0r + bcol + (wc * 2 + 0) * 32 + l31] = acc00[r] + bv0;
    C[m0r + bcol + (wc * 2 + 1) * 32 + l31] = acc01[r] + bv1;
    C[m1r + bcol + (wc * 2 + 0) * 32 + l31] = acc10[r] + bv0;
    C[m1r + bcol + (wc * 2 + 1) * 32 + l31] = acc11[r] + bv1;
  }
#undef LOAD_TILE
#undef WRITE_TILE
}

extern "C" void kernel_launch(void* const* d_in, const int* in_sizes, int n_in,
                              void* d_out, int out_size, void* d_ws, size_t ws_size,
                              hipStream_t stream) {
  const float* Q_input = (const float*)d_in[0];
  const float* K = (const float*)d_in[1];
  const float* V = (const float*)d_in[2];
  const float* Wq_w = (const float*)d_in[4];
  const float* Wq_b = (const float*)d_in[5];
  const float* Wo_w = (const float*)d_in[6];
  const float* Wo_b = (const float*)d_in[7];
  const float* proj_w = (const float*)d_in[8];
  const float* proj_b = (const float*)d_in[9];
  const float* geo_w = (const float*)d_in[10];
  const float* temp = (const float*)d_in[11];

  float* ws = (float*)d_ws;
  float* M = ws;                          // 98304 f32
  float* cbias = M + 98304;               // 128
  float* qn2 = cbias + 128;               // 16384
  float* kn2 = qn2 + 16384;               // 16384
  f16* pqF = (f16*)(kn2 + 16384);
  f16* pkF = (f16*)(kn2 + 16384 + 131072);
  f16* Vt = (f16*)(kn2 + 16384 + 262144);
  f16* attnF = (f16*)(kn2 + 16384 + 262144 + 2097152);
  f16* Wf = (f16*)(kn2 + 16384 + 262144 + 2097152 + 2097152);
  float* out = (float*)d_out;

  k_fuse<<<dim3(384), dim3(256), 0, stream>>>(Wq_w, proj_w, M);
  k_fuse_bias<<<dim3(1), dim3(128), 0, stream>>>(Wq_b, proj_w, proj_b, cbias);
  k_wcvt<<<dim3(512), dim3(256), 0, stream>>>(Wo_w, Wf);
  k_vt<<<dim3(32, 4, 8), dim3(256), 0, stream>>>(V, Vt);
  k_genq<<<dim3(512), dim3(128), 0, stream>>>(Q_input, M, cbias, pqF, qn2);
  k_genk<<<dim3(512), dim3(128), 0, stream>>>(K, proj_w, proj_b, pkF, kn2);
  k_attn<<<dim3(512), dim3(512), 0, stream>>>(pqF, qn2, pkF, kn2, Vt, geo_w, temp, attnF);
  k_wo<<<dim3(8, 32), dim3(256), 0, stream>>>(attnF, Wf, Wo_b, out);
}

// Round 7
// 208.124 us; speedup vs baseline: 3.0590x; 1.0346x over previous
//
#include <hip/hip_runtime.h>
#include <hip/hip_bf16.h>
#include <math.h>

#define B_ 2
#define S_ 2048
#define D_ 1024
#define H_ 4
#define DK_ 256
#define NJ 24
#define NG 96
#define KTA 128
#define NT2 (S_ / KTA)

typedef _Float16 f16;
typedef _Float16 f16x2 __attribute__((ext_vector_type(2)));
typedef _Float16 f16x8 __attribute__((ext_vector_type(8)));
typedef float f32x16 __attribute__((ext_vector_type(16)));

// ---------------- kernel 1: fold Wq into proj (M transposed: [hj][d]) ----------------
__global__ __launch_bounds__(256) void k_fuse(const float* __restrict__ Wq_w,
                                              const float* __restrict__ proj_w,
                                              float* __restrict__ M) {
  int tid = blockIdx.x * 256 + threadIdx.x;
  int hj = tid >> 10;
  int d = tid & 1023;
  int h = hj / NJ, j = hj - h * NJ;
  const float* wq = Wq_w + (size_t)(h * DK_) * D_ + d;
  const float* pw = proj_w + j * DK_;
  float acc = 0.f;
#pragma unroll 8
  for (int k = 0; k < DK_; ++k) acc += wq[(size_t)k * D_] * pw[k];
  M[(size_t)hj * D_ + d] = acc;
}

__global__ void k_fuse_bias(const float* __restrict__ Wq_b,
                            const float* __restrict__ proj_w,
                            const float* __restrict__ proj_b,
                            float* __restrict__ cbias) {
  int hj = threadIdx.x;
  if (hj < NG) {
    int h = hj / NJ, j = hj - h * NJ;
    float acc = proj_b[j];
    for (int k = 0; k < DK_; ++k) acc += Wq_b[h * DK_ + k] * proj_w[j * DK_ + k];
    cbias[hj] = acc;
  }
}

// ---------------- W -> f16 convert ----------------
__global__ __launch_bounds__(256) void k_wcvt(const float* __restrict__ W,
                                              f16* __restrict__ Wt) {
  int i = (blockIdx.x * 256 + threadIdx.x) * 8;
  float4 a = *(const float4*)(W + i);
  float4 b = *(const float4*)(W + i + 4);
  f16x8 o = {(f16)a.x, (f16)a.y, (f16)a.z, (f16)a.w,
             (f16)b.x, (f16)b.y, (f16)b.z, (f16)b.w};
  *(f16x8*)(Wt + i) = o;
}

// ---------------- V transpose + f16: Vt[bh][vc 256][s 2048] ----------------
__global__ __launch_bounds__(256) void k_vt(const float* __restrict__ V,
                                            f16* __restrict__ Vt) {
  __shared__ f16 tile[64][72];
  int t = threadIdx.x;
  int s0 = blockIdx.x * 64, c0 = blockIdx.y * 64;
  int bh = blockIdx.z;
  int b = bh >> 2, h = bh & 3;
  const float* src = V + (size_t)b * S_ * D_ + h * DK_ + c0;
#pragma unroll
  for (int u = 0; u < 4; ++u) {
    int row = (t >> 4) + 16 * u;
    int c4 = (t & 15) * 4;
    float4 v = *(const float4*)(src + (size_t)(s0 + row) * D_ + c4);
    tile[c4 + 0][row] = (f16)v.x;
    tile[c4 + 1][row] = (f16)v.y;
    tile[c4 + 2][row] = (f16)v.z;
    tile[c4 + 3][row] = (f16)v.w;
  }
  __syncthreads();
  int vc = t & 63, seg = t >> 6;
  f16* dst = Vt + ((size_t)bh * DK_ + c0 + vc) * S_ + s0 + seg * 16;
  *(f16x8*)dst = *(f16x8*)&tile[vc][seg * 16];
  *(f16x8*)(dst + 8) = *(f16x8*)&tile[vc][seg * 16 + 8];
}

// ---------------- psi from gen rows (8 rows per block), f16 out ----------------
__device__ __forceinline__ void psi_store(const float (*genL)[NG], int t, int g0,
                                          f16* __restrict__ po,
                                          float* __restrict__ n2o) {
  if (t < 64) {
    int h = t >> 4, ii = t & 15, j = ii & 7;
#pragma unroll 2
    for (int r = 0; r < 8; ++r) {
      int g = g0 + r;
      int b = g >> 11, s = g & (S_ - 1);
      const float* gl = genL[r] + h * NJ;
      float A = gl[j], Bg = gl[8 + j];
      float Th = fminf(fmaxf(gl[16 + j], -8.f), 8.f);
      float val = (ii < 8) ? (A * expf(Th) + Bg * cosf(Th)) : (Bg * sinf(Th));
      size_t base = (size_t)(b * H_ + h) * S_ + s;
      po[base * 16 + ii] = (f16)val;
      float sq = val * val;
#pragma unroll
      for (int off = 1; off < 16; off <<= 1) sq += __shfl_xor(sq, off);
      if (ii == 0) n2o[base] = sq;
    }
  }
}

// ---------------- gen_q = Q_input @ M^T + cbias, then psi ----------------
__global__ __launch_bounds__(128) void k_genq(const float* __restrict__ Q,
                                              const float* __restrict__ M,
                                              const float* __restrict__ cbias,
                                              f16* __restrict__ pqF,
                                              float* __restrict__ qn2) {
  __shared__ __align__(16) float qlds[8][D_];
  __shared__ float genL[8][NG];
  int t = threadIdx.x;
  int g0 = blockIdx.x * 8;
  {
    const float4* src = (const float4*)(Q + (size_t)g0 * D_);
    float4* dst = (float4*)&qlds[0][0];
#pragma unroll
    for (int u = 0; u < 16; ++u) dst[t + 128 * u] = src[t + 128 * u];
  }
  __syncthreads();
  if (t < NG) {
    float cb = cbias[t];
    float acc[8];
#pragma unroll
    for (int r = 0; r < 8; ++r) acc[r] = cb;
    const float* Mp = M + (size_t)t * D_;
#pragma unroll 2
    for (int d0 = 0; d0 < D_; d0 += 4) {
      float4 m4 = *(const float4*)(Mp + d0);
#pragma unroll
      for (int r = 0; r < 8; ++r) {
        float4 q4 = *(const float4*)&qlds[r][d0];
        acc[r] += q4.x * m4.x + q4.y * m4.y + q4.z * m4.z + q4.w * m4.w;
      }
    }
#pragma unroll
    for (int r = 0; r < 8; ++r) genL[r][t] = acc[r];
  }
  __syncthreads();
  psi_store(genL, t, g0, pqF, qn2);
}

// ---------------- gen_k = K_head @ proj_w.T + proj_b, then psi ----------------
__global__ __launch_bounds__(128) void k_genk(const float* __restrict__ Kin,
                                              const float* __restrict__ proj_w,
                                              const float* __restrict__ proj_b,
                                              f16* __restrict__ pkF,
                                              float* __restrict__ kn2) {
  __shared__ __align__(16) float klds[8][D_];
  __shared__ float genL[8][NG];
  __shared__ float pwT[DK_][NJ];
  int t = threadIdx.x;
  int g0 = blockIdx.x * 8;
  {
    const float4* src = (const float4*)(Kin + (size_t)g0 * D_);
    float4* dst = (float4*)&klds[0][0];
#pragma unroll
    for (int u = 0; u < 16; ++u) dst[t + 128 * u] = src[t + 128 * u];
  }
  for (int idx = t; idx < NJ * DK_; idx += 128) {
    int j = idx >> 8, c = idx & 255;
    pwT[c][j] = proj_w[idx];
  }
  __syncthreads();
  if (t < NG) {
    int h = t / NJ, j = t - h * NJ;
    float pb = proj_b[j];
    float acc[8];
#pragma unroll
    for (int r = 0; r < 8; ++r) acc[r] = pb;
#pragma unroll 2
    for (int c0 = 0; c0 < DK_; c0 += 4) {
      float w0 = pwT[c0][j], w1 = pwT[c0 + 1][j];
      float w2 = pwT[c0 + 2][j], w3 = pwT[c0 + 3][j];
#pragma unroll
      for (int r = 0; r < 8; ++r) {
        float4 k4 = *(const float4*)&klds[r][h * DK_ + c0];
        acc[r] += k4.x * w0 + k4.y * w1 + k4.z * w2 + k4.w * w3;
      }
    }
#pragma unroll
    for (int r = 0; r < 8; ++r) genL[r][t] = acc[r];
  }
  __syncthreads();
  psi_store(genL, t, g0, pkF, kn2);
}

// ---------------- MFMA flash geometric attention (reg-prefetched) ----------------
// 8 waves, QT=32, KT=128. Scores swapped: A=[psi_k;J psi_k], B=psi_q.
// V B-frags are wave-private -> register prefetch (no LDS staging).
// Plds chunk-major [16][32][8]: bank-balanced b128 reads/writes.
__global__ __launch_bounds__(512, 4) void k_attn(
    const f16* __restrict__ pqF, const float* __restrict__ qn2,
    const f16* __restrict__ pkF, const float* __restrict__ kn2,
    const f16* __restrict__ Vt, const float* __restrict__ geo_w,
    const float* __restrict__ temp, f16* __restrict__ attn_out) {
  __shared__ float kn2s[KTA], khs[KTA];
  __shared__ float mPart[8][32], sPart[8][32];
  __shared__ float mbuf[2][32], fL[32], lfin[32];
  __shared__ __align__(16) f16 Plds[16][32][8];  // [k-chunk][q][8]

  const int t = threadIdx.x;
  const int w = t >> 6;
  const int lane = t & 63;
  const int q_ = lane & 31;
  const int lh = lane >> 5;

  const int bid = blockIdx.x;
  const int bh = bid & 7, qt = bid >> 3;
  const int h = bh & 3, b = bh >> 2;
  const int q0 = qt * 32;

  const size_t bhS = (size_t)bh * S_;
  const f16* pkb = pkF + bhS * 16;
  const float* kn2b = kn2 + bhS;

  const float scale = 0.25f / temp[0];
  const float g0s = geo_w[0] * scale, g1s = geo_w[1] * scale, g2s = geo_w[2] * scale;
  const float g3s = geo_w[3] * scale;

  const f16x8 bq = *(const f16x8*)(pqF + (bhS + q0 + q_) * 16 + lh * 8);
  const float qn2q = qn2[bhS + q0 + q_];
  const float qh3 = sqrtf(qn2q + 1e-6f) * g3s;

  // per-lane fragment pointers
  const f16* ap_base = pkb + (size_t)(w * 16 + (q_ & 15)) * 16 +
                       ((q_ < 16) ? lh * 8 : (1 - lh) * 8);
  const f16* vb_base = Vt + ((size_t)bh * DK_ + w * 32 + q_) * S_ + lh * 8;

  if (t < KTA) { float kv = kn2b[t]; kn2s[t] = kv; khs[t] = sqrtf(kv + 1e-6f); }
  if (t < 32) mbuf[0][t] = -INFINITY;
  float lreg = 0.f;
  f32x16 acc{};
  const f32x16 zacc{};

  // prologue prefetch: af(0), bv(0)
  f16x8 af = *(const f16x8*)ap_base;
  f16x8 bv[8];
#pragma unroll
  for (int ks = 0; ks < 8; ++ks) bv[ks] = *(const f16x8*)(vb_base + ks * 16);
  __syncthreads();

  for (int kt = 0; kt < NT2; ++kt) {
    const int k0 = kt * KTA;

    // ---- prefetch next kn2 into reg (t<128) ----
    float knv = 0.f;
    if (t < KTA && kt + 1 < NT2) knv = kn2b[k0 + KTA + t];

    // ---- scores ----
    f16x8 afx = af;
    if (q_ >= 16 && lh == 1) afx = -afx;
    f32x16 sc = __builtin_amdgcn_mfma_f32_32x32x16_f16(afx, bq, zacc, 0, 0, 0);
    // prefetch next af
    if (kt + 1 < NT2) af = *(const f16x8*)(ap_base + (size_t)(k0 + KTA) * 16);

    float sv[8];
    float tmax = -INFINITY;
#pragma unroll
    for (int r = 0; r < 8; ++r) {
      const int kk = (r & 3) + 8 * (r >> 2) + 4 * lh;
      float tn = sc[r], sp = sc[r + 8];
      float wr = qn2q * kn2s[w * 16 + kk] - tn * tn - sp * sp;
      float wg = sqrtf(fmaxf(wr, 0.f) + 1e-6f);
      sv[r] = g0s * wg + g1s * tn + g2s * sp + qh3 * khs[w * 16 + kk];
      tmax = fmaxf(tmax, sv[r]);
    }
    tmax = fmaxf(tmax, __shfl_xor(tmax, 32));
    if (lh == 0) mPart[w][q_] = tmax;
    __syncthreads();  // bar1

    float mold = mbuf[kt & 1][q_];
    float mn = mold;
#pragma unroll
    for (int i = 0; i < 8; ++i) mn = fmaxf(mn, mPart[i][q_]);
    if (t < KTA && kt + 1 < NT2) {
      kn2s[t] = knv;
      khs[t] = sqrtf(knv + 1e-6f);
    }
    float pv[8];
    float ps = 0.f;
#pragma unroll
    for (int r = 0; r < 8; ++r) { pv[r] = __expf(sv[r] - mn); ps += pv[r]; }
    ps += __shfl_xor(ps, 32);
    if (lh == 0) sPart[w][q_] = ps;
    if (w == 0 && lh == 0) {
      mbuf[(kt & 1) ^ 1][q_] = mn;
      fL[q_] = __expf(mold - mn);
    }
    {
      f16x2 p01 = {(f16)pv[0], (f16)pv[1]};
      f16x2 p23 = {(f16)pv[2], (f16)pv[3]};
      f16x2 p45 = {(f16)pv[4], (f16)pv[5]};
      f16x2 p67 = {(f16)pv[6], (f16)pv[7]};
      *(f16x2*)&Plds[2 * w + 0][q_][4 * lh + 0] = p01;
      *(f16x2*)&Plds[2 * w + 0][q_][4 * lh + 2] = p23;
      *(f16x2*)&Plds[2 * w + 1][q_][4 * lh + 0] = p45;
      *(f16x2*)&Plds[2 * w + 1][q_][4 * lh + 2] = p67;
    }
    __syncthreads();  // bar2

    // ---- PV ----
#pragma unroll
    for (int r = 0; r < 16; ++r) acc[r] *= fL[(r & 3) + 8 * (r >> 2) + 4 * lh];
    if (w == 0 && lh == 0) {
      float s8 = 0.f;
#pragma unroll
      for (int i = 0; i < 8; ++i) s8 += sPart[i][q_];
      lreg = lreg * fL[q_] + s8;
    }
#pragma unroll
    for (int ks = 0; ks < 8; ++ks) {
      f16x8 pa = *(const f16x8*)&Plds[2 * ks + lh][q_][0];
      acc = __builtin_amdgcn_mfma_f32_32x32x16_f16(pa, bv[ks], acc, 0, 0, 0);
    }
    // prefetch next-tile V fragments (regs only; hidden under next scores+softmax)
    if (kt + 1 < NT2) {
      const f16* vbn = vb_base + (k0 + KTA);
#pragma unroll
      for (int ks = 0; ks < 8; ++ks) bv[ks] = *(const f16x8*)(vbn + ks * 16);
    }
  }

  if (w == 0 && lh == 0) lfin[q_] = 1.f / lreg;
  __syncthreads();
  const size_t obase = ((size_t)b * S_ + q0) * D_ + h * DK_ + w * 32 + q_;
#pragma unroll
  for (int r = 0; r < 16; ++r) {
    const int row = (r & 3) + 8 * (r >> 2) + 4 * lh;
    attn_out[obase + (size_t)row * D_] = (f16)(acc[r] * lfin[row]);
  }
}

// ---------------- output projection: LDS-staged f16 MFMA GEMM ----------------
__global__ __launch_bounds__(256, 1) void k_wo(const f16* __restrict__ A,
                                               const f16* __restrict__ Wt,
                                               const float* __restrict__ bias,
                                               float* __restrict__ C) {
  __shared__ __align__(16) f16 Abuf[2][128 * 64];
  __shared__ __align__(16) f16 Bbuf[2][128 * 64];
  const int t = threadIdx.x;
  const int w = t >> 6, lane = t & 63;
  const int wr = w >> 1, wc = w & 1;
  const int brow = blockIdx.y * 128, bcol = blockIdx.x * 128;

  int srow[4], skof[4];
#pragma unroll
  for (int u = 0; u < 4; ++u) {
    int c = t + 256 * u;
    int sub = c >> 6, l6 = c & 63;
    srow[u] = (sub >> 2) * 32 + (l6 & 31);
    skof[u] = (sub & 3) * 16 + (l6 >> 5) * 8;
  }

  uint4 ra0, ra1, ra2, ra3, rb0, rb1, rb2, rb3;
#define LOAD_TILE(K0)                                                        \
  {                                                                          \
    ra0 = *(const uint4*)(A + (size_t)(brow + srow[0]) * D_ + (K0) + skof[0]); \
    ra1 = *(const uint4*)(A + (size_t)(brow + srow[1]) * D_ + (K0) + skof[1]); \
    ra2 = *(const uint4*)(A + (size_t)(brow + srow[2]) * D_ + (K0) + skof[2]); \
    ra3 = *(const uint4*)(A + (size_t)(brow + srow[3]) * D_ + (K0) + skof[3]); \
    rb0 = *(const uint4*)(Wt + (size_t)(bcol + srow[0]) * D_ + (K0) + skof[0]); \
    rb1 = *(const uint4*)(Wt + (size_t)(bcol + srow[1]) * D_ + (K0) + skof[1]); \
    rb2 = *(const uint4*)(Wt + (size_t)(bcol + srow[2]) * D_ + (K0) + skof[2]); \
    rb3 = *(const uint4*)(Wt + (size_t)(bcol + srow[3]) * D_ + (K0) + skof[3]); \
  }
#define WRITE_TILE(BUF)                                       \
  {                                                           \
    *(uint4*)&Abuf[BUF][(t + 0) * 8] = ra0;                   \
    *(uint4*)&Abuf[BUF][(t + 256) * 8] = ra1;                 \
    *(uint4*)&Abuf[BUF][(t + 512) * 8] = ra2;                 \
    *(uint4*)&Abuf[BUF][(t + 768) * 8] = ra3;                 \
    *(uint4*)&Bbuf[BUF][(t + 0) * 8] = rb0;                   \
    *(uint4*)&Bbuf[BUF][(t + 256) * 8] = rb1;                 \
    *(uint4*)&Bbuf[BUF][(t + 512) * 8] = rb2;                 \
    *(uint4*)&Bbuf[BUF][(t + 768) * 8] = rb3;                 \
  }

  f32x16 acc00{}, acc01{}, acc10{}, acc11{};

  LOAD_TILE(0);
  WRITE_TILE(0);
  LOAD_TILE(64);
  __syncthreads();

  int cur = 0;
  for (int kt = 0; kt < 16; ++kt) {
    const int am0 = (wr * 2 + 0) * 4, am1 = (wr * 2 + 1) * 4;
    const int bn0 = (wc * 2 + 0) * 4, bn1 = (wc * 2 + 1) * 4;
#pragma unroll
    for (int kk = 0; kk < 4; ++kk) {
      f16x8 a0 = *(const f16x8*)&Abuf[cur][(am0 + kk) * 512 + lane * 8];
      f16x8 a1 = *(const f16x8*)&Abuf[cur][(am1 + kk) * 512 + lane * 8];
      f16x8 b0 = *(const f16x8*)&Bbuf[cur][(bn0 + kk) * 512 + lane * 8];
      f16x8 b1 = *(const f16x8*)&Bbuf[cur][(bn1 + kk) * 512 + lane * 8];
      acc00 = __builtin_amdgcn_mfma_f32_32x32x16_f16(a0, b0, acc00, 0, 0, 0);
      acc01 = __builtin_amdgcn_mfma_f32_32x32x16_f16(a0, b1, acc01, 0, 0, 0);
      acc10 = __builtin_amdgcn_mfma_f32_32x32x16_f16(a1, b0, acc10, 0, 0, 0);
      acc11 = __builtin_amdgcn_mfma_f32_32x32x16_f16(a1, b1, acc11, 0, 0, 0);
    }
    if (kt + 1 < 16) {
      WRITE_TILE(cur ^ 1);
      if (kt + 2 < 16) LOAD_TILE((kt + 2) * 64);
    }
    __syncthreads();
    cur ^= 1;
  }

  const int l31 = lane & 31, lh = lane >> 5;
  const float bv0 = bias[bcol + (wc * 2 + 0) * 32 + l31];
  const float bv1 = bias[bcol + (wc * 2 + 1) * 32 + l31];
#pragma unroll
  for (int r = 0; r < 16; ++r) {
    const int row = (r & 3) + 8 * (r >> 2) + 4 * lh;
    const size_t m0r = (size_t)(brow + (wr * 2 + 0) * 32 + row) * D_;
    const size_t m1r = (size_t)(brow + (wr * 2 + 1) * 32 + row) * D_;
    C[m0r + bcol + (wc * 2 + 0) * 32 + l31] = acc00[r] + bv0;
    C[m0r + bcol + (wc * 2 + 1) * 32 + l31] = acc01[r] + bv1;
    C[m1r + bcol + (wc * 2 + 0) * 32 + l31] = acc10[r] + bv0;
    C[m1r + bcol + (wc * 2 + 1) * 32 + l31] = acc11[r] + bv1;
  }
#undef LOAD_TILE
#undef WRITE_TILE
}

extern "C" void kernel_launch(void* const* d_in, const int* in_sizes, int n_in,
                              void* d_out, int out_size, void* d_ws, size_t ws_size,
                              hipStream_t stream) {
  const float* Q_input = (const float*)d_in[0];
  const float* K = (const float*)d_in[1];
  const float* V = (const float*)d_in[2];
  const float* Wq_w = (const float*)d_in[4];
  const float* Wq_b = (const float*)d_in[5];
  const float* Wo_w = (const float*)d_in[6];
  const float* Wo_b = (const float*)d_in[7];
  const float* proj_w = (const float*)d_in[8];
  const float* proj_b = (const float*)d_in[9];
  const float* geo_w = (const float*)d_in[10];
  const float* temp = (const float*)d_in[11];

  float* ws = (float*)d_ws;
  float* M = ws;                          // 98304 f32 (now [hj][d])
  float* cbias = M + 98304;               // 128
  float* qn2 = cbias + 128;               // 16384
  float* kn2 = qn2 + 16384;               // 16384
  f16* pqF = (f16*)(kn2 + 16384);
  f16* pkF = (f16*)(kn2 + 16384 + 131072);
  f16* Vt = (f16*)(kn2 + 16384 + 262144);
  f16* attnF = (f16*)(kn2 + 16384 + 262144 + 2097152);
  f16* Wf = (f16*)(kn2 + 16384 + 262144 + 2097152 + 2097152);
  float* out = (float*)d_out;

  k_fuse<<<dim3(384), dim3(256), 0, stream>>>(Wq_w, proj_w, M);
  k_fuse_bias<<<dim3(1), dim3(128), 0, stream>>>(Wq_b, proj_w, proj_b, cbias);
  k_wcvt<<<dim3(512), dim3(256), 0, stream>>>(Wo_w, Wf);
  k_vt<<<dim3(32, 4, 8), dim3(256), 0, stream>>>(V, Vt);
  k_genq<<<dim3(512), dim3(128), 0, stream>>>(Q_input, M, cbias, pqF, qn2);
  k_genk<<<dim3(512), dim3(128), 0, stream>>>(K, proj_w, proj_b, pkF, kn2);
  k_attn<<<dim3(512), dim3(512), 0, stream>>>(pqF, qn2, pkF, kn2, Vt, geo_w, temp, attnF);
  k_wo<<<dim3(8, 32), dim3(256), 0, stream>>>(attnF, Wf, Wo_b, out);
}

// Round 8
// 191.752 us; speedup vs baseline: 3.3202x; 1.0854x over previous
//
#include <hip/hip_runtime.h>
#include <hip/hip_bf16.h>
#include <math.h>

#define B_ 2
#define S_ 2048
#define D_ 1024
#define H_ 4
#define DK_ 256
#define NJ 24
#define NG 96
#define KTA 128
#define NT2 (S_ / KTA)

typedef _Float16 f16;
typedef _Float16 f16x2 __attribute__((ext_vector_type(2)));
typedef _Float16 f16x8 __attribute__((ext_vector_type(8)));
typedef float f32x16 __attribute__((ext_vector_type(16)));
typedef float v2f __attribute__((ext_vector_type(2)));

// ---------------- kernel 1: fold Wq into proj (M transposed: [hj][d]) ----------------
__global__ __launch_bounds__(256) void k_fuse(const float* __restrict__ Wq_w,
                                              const float* __restrict__ proj_w,
                                              float* __restrict__ M) {
  int tid = blockIdx.x * 256 + threadIdx.x;
  int hj = tid >> 10;
  int d = tid & 1023;
  int h = hj / NJ, j = hj - h * NJ;
  const float* wq = Wq_w + (size_t)(h * DK_) * D_ + d;
  const float* pw = proj_w + j * DK_;
  float acc = 0.f;
#pragma unroll 8
  for (int k = 0; k < DK_; ++k) acc += wq[(size_t)k * D_] * pw[k];
  M[(size_t)hj * D_ + d] = acc;
}

__global__ void k_fuse_bias(const float* __restrict__ Wq_b,
                            const float* __restrict__ proj_w,
                            const float* __restrict__ proj_b,
                            float* __restrict__ cbias) {
  int hj = threadIdx.x;
  if (hj < NG) {
    int h = hj / NJ, j = hj - h * NJ;
    float acc = proj_b[j];
    for (int k = 0; k < DK_; ++k) acc += Wq_b[h * DK_ + k] * proj_w[j * DK_ + k];
    cbias[hj] = acc;
  }
}

// ---------------- W -> f16 convert ----------------
__global__ __launch_bounds__(256) void k_wcvt(const float* __restrict__ W,
                                              f16* __restrict__ Wt) {
  int i = (blockIdx.x * 256 + threadIdx.x) * 8;
  float4 a = *(const float4*)(W + i);
  float4 b = *(const float4*)(W + i + 4);
  f16x8 o = {(f16)a.x, (f16)a.y, (f16)a.z, (f16)a.w,
             (f16)b.x, (f16)b.y, (f16)b.z, (f16)b.w};
  *(f16x8*)(Wt + i) = o;
}

// ---------------- V transpose + f16: Vt[bh][vc 256][s 2048] ----------------
__global__ __launch_bounds__(256) void k_vt(const float* __restrict__ V,
                                            f16* __restrict__ Vt) {
  __shared__ f16 tile[64][72];
  int t = threadIdx.x;
  int s0 = blockIdx.x * 64, c0 = blockIdx.y * 64;
  int bh = blockIdx.z;
  int b = bh >> 2, h = bh & 3;
  const float* src = V + (size_t)b * S_ * D_ + h * DK_ + c0;
#pragma unroll
  for (int u = 0; u < 4; ++u) {
    int row = (t >> 4) + 16 * u;
    int c4 = (t & 15) * 4;
    float4 v = *(const float4*)(src + (size_t)(s0 + row) * D_ + c4);
    tile[c4 + 0][row] = (f16)v.x;
    tile[c4 + 1][row] = (f16)v.y;
    tile[c4 + 2][row] = (f16)v.z;
    tile[c4 + 3][row] = (f16)v.w;
  }
  __syncthreads();
  int vc = t & 63, seg = t >> 6;
  f16* dst = Vt + ((size_t)bh * DK_ + c0 + vc) * S_ + s0 + seg * 16;
  *(f16x8*)dst = *(f16x8*)&tile[vc][seg * 16];
  *(f16x8*)(dst + 8) = *(f16x8*)&tile[vc][seg * 16 + 8];
}

// ---------------- psi from gen rows (8 rows per block), f16 out ----------------
__device__ __forceinline__ void psi_store(const float (*genL)[NG], int t, int g0,
                                          f16* __restrict__ po,
                                          float* __restrict__ n2o) {
  if (t < 64) {
    int h = t >> 4, ii = t & 15, j = ii & 7;
#pragma unroll 2
    for (int r = 0; r < 8; ++r) {
      int g = g0 + r;
      int b = g >> 11, s = g & (S_ - 1);
      const float* gl = genL[r] + h * NJ;
      float A = gl[j], Bg = gl[8 + j];
      float Th = fminf(fmaxf(gl[16 + j], -8.f), 8.f);
      float val = (ii < 8) ? (A * expf(Th) + Bg * cosf(Th)) : (Bg * sinf(Th));
      size_t base = (size_t)(b * H_ + h) * S_ + s;
      po[base * 16 + ii] = (f16)val;
      float sq = val * val;
#pragma unroll
      for (int off = 1; off < 16; off <<= 1) sq += __shfl_xor(sq, off);
      if (ii == 0) n2o[base] = sq;
    }
  }
}

// ---------------- fused gen_q / gen_k (block-uniform branch) ----------------
// blocks 0..511: Q path (gen = Q_input @ M^T + cbias)
// blocks 512..1023: K path (gen = K_head @ proj_w^T + proj_b)
__global__ __launch_bounds__(128) void k_genqk(
    const float* __restrict__ Q, const float* __restrict__ Kin,
    const float* __restrict__ M, const float* __restrict__ cbias,
    const float* __restrict__ proj_w, const float* __restrict__ proj_b,
    f16* __restrict__ pqF, float* __restrict__ qn2,
    f16* __restrict__ pkF, float* __restrict__ kn2) {
  __shared__ __align__(16) float xlds[8][D_];
  __shared__ float genL[8][NG];
  int t = threadIdx.x;
  const bool isQ = blockIdx.x < 512;
  const int g0 = (isQ ? blockIdx.x : blockIdx.x - 512) * 8;
  {
    const float4* src = (const float4*)((isQ ? Q : Kin) + (size_t)g0 * D_);
    float4* dst = (float4*)&xlds[0][0];
#pragma unroll
    for (int u = 0; u < 16; ++u) dst[t + 128 * u] = src[t + 128 * u];
  }
  __syncthreads();
  if (t < NG) {
    int h = t / NJ, j = t - h * NJ;
    float acc[8];
    if (isQ) {
      float cb = cbias[t];
#pragma unroll
      for (int r = 0; r < 8; ++r) acc[r] = cb;
      const float* Mp = M + (size_t)t * D_;
#pragma unroll 2
      for (int d0 = 0; d0 < D_; d0 += 4) {
        float4 m4 = *(const float4*)(Mp + d0);
#pragma unroll
        for (int r = 0; r < 8; ++r) {
          float4 q4 = *(const float4*)&xlds[r][d0];
          acc[r] += q4.x * m4.x + q4.y * m4.y + q4.z * m4.z + q4.w * m4.w;
        }
      }
    } else {
      float pb = proj_b[j];
#pragma unroll
      for (int r = 0; r < 8; ++r) acc[r] = pb;
      const float* pwj = proj_w + (size_t)j * DK_;
#pragma unroll 2
      for (int c0 = 0; c0 < DK_; c0 += 4) {
        float4 w4 = *(const float4*)(pwj + c0);
#pragma unroll
        for (int r = 0; r < 8; ++r) {
          float4 k4 = *(const float4*)&xlds[r][h * DK_ + c0];
          acc[r] += k4.x * w4.x + k4.y * w4.y + k4.z * w4.z + k4.w * w4.w;
        }
      }
    }
#pragma unroll
    for (int r = 0; r < 8; ++r) genL[r][t] = acc[r];
  }
  __syncthreads();
  if (isQ) psi_store(genL, t, g0, pqF, qn2);
  else     psi_store(genL, t, g0, pkF, kn2);
}

// ---------------- MFMA flash geometric attention (packed-f32 softmax) ----------------
__global__ __launch_bounds__(512, 4) void k_attn(
    const f16* __restrict__ pqF, const float* __restrict__ qn2,
    const f16* __restrict__ pkF, const float* __restrict__ kn2,
    const f16* __restrict__ Vt, const float* __restrict__ geo_w,
    const float* __restrict__ temp, f16* __restrict__ attn_out) {
  __shared__ __align__(16) float kn2s[KTA];
  __shared__ __align__(16) float khs[KTA];
  __shared__ float mPart[8][32], sPart[8][32];
  __shared__ float mbuf[2][32];
  __shared__ __align__(16) float fL[32], lfin[32];
  __shared__ __align__(16) f16 Plds[16][32][8];  // [k-chunk][q][8]

  const int t = threadIdx.x;
  const int w = t >> 6;
  const int lane = t & 63;
  const int q_ = lane & 31;
  const int lh = lane >> 5;

  const int bid = blockIdx.x;
  const int bh = bid & 7, qt = bid >> 3;
  const int h = bh & 3, b = bh >> 2;
  const int q0 = qt * 32;

  const size_t bhS = (size_t)bh * S_;
  const f16* pkb = pkF + bhS * 16;
  const float* kn2b = kn2 + bhS;

  const float scale = 0.25f / temp[0];
  const float g0s = geo_w[0] * scale, g1s = geo_w[1] * scale, g2s = geo_w[2] * scale;
  const float g3s = geo_w[3] * scale;

  const f16x8 bq = *(const f16x8*)(pqF + (bhS + q0 + q_) * 16 + lh * 8);
  const float qn2q = qn2[bhS + q0 + q_];
  const float qh3 = sqrtf(qn2q + 1e-6f) * g3s;

  // packed splats
  const v2f qn2v = {qn2q, qn2q};
  const v2f g0v = {g0s, g0s}, g1v = {g1s, g1s}, g2v = {g2s, g2s};
  const v2f qh3v = {qh3, qh3};
  const v2f zero2 = {0.f, 0.f}, eps2 = {1e-6f, 1e-6f};

  // per-lane fragment pointers
  const f16* ap_base = pkb + (size_t)(w * 16 + (q_ & 15)) * 16 +
                       ((q_ < 16) ? lh * 8 : (1 - lh) * 8);
  const f16* vb_base = Vt + ((size_t)bh * DK_ + w * 32 + q_) * S_ + lh * 8;

  if (t < KTA) { float kv = kn2b[t]; kn2s[t] = kv; khs[t] = sqrtf(kv + 1e-6f); }
  if (t < 32) mbuf[0][t] = -INFINITY;
  float lreg = 0.f;
  f32x16 acc{};
  const f32x16 zacc{};

  // prologue prefetch: af(0), bv(0)
  f16x8 af = *(const f16x8*)ap_base;
  f16x8 bv[8];
#pragma unroll
  for (int ks = 0; ks < 8; ++ks) bv[ks] = *(const f16x8*)(vb_base + ks * 16);
  __syncthreads();

  for (int kt = 0; kt < NT2; ++kt) {
    const int k0 = kt * KTA;

    // ---- prefetch next kn2 into reg (t<128) ----
    float knv = 0.f;
    if (t < KTA && kt + 1 < NT2) knv = kn2b[k0 + KTA + t];

    // ---- scores ----
    f16x8 afx = af;
    if (q_ >= 16 && lh == 1) afx = -afx;
    f32x16 sc = __builtin_amdgcn_mfma_f32_32x32x16_f16(afx, bq, zacc, 0, 0, 0);
    // prefetch next af
    if (kt + 1 < NT2) af = *(const f16x8*)(ap_base + (size_t)(k0 + KTA) * 16);

    // packed sv: pairs (r, r+1); kk(r)=(r&3)+8*(r>>2)+4*lh consecutive in pair
    v2f svv[4];
    v2f tmaxv = {-INFINITY, -INFINITY};
#pragma unroll
    for (int rp = 0; rp < 4; ++rp) {
      const int r = 2 * rp;
      const int kb2 = w * 16 + 4 * lh + (rp & 1) * 2 + (rp >> 1) * 8;
      v2f tn = {sc[r], sc[r + 1]};
      v2f sp = {sc[r + 8], sc[r + 9]};
      v2f kn2p = *(const v2f*)&kn2s[kb2];
      v2f khp = *(const v2f*)&khs[kb2];
      v2f wr = qn2v * kn2p - tn * tn - sp * sp;
      wr = __builtin_elementwise_max(wr, zero2) + eps2;
      v2f wg = {sqrtf(wr.x), sqrtf(wr.y)};
      v2f sv2 = g0v * wg + g1v * tn + g2v * sp + qh3v * khp;
      svv[rp] = sv2;
      tmaxv = __builtin_elementwise_max(tmaxv, sv2);
    }
    float tmax = fmaxf(tmaxv.x, tmaxv.y);
    tmax = fmaxf(tmax, __shfl_xor(tmax, 32));
    if (lh == 0) mPart[w][q_] = tmax;
    __syncthreads();  // bar1

    float mold = mbuf[kt & 1][q_];
    float mn = mold;
#pragma unroll
    for (int i = 0; i < 8; ++i) mn = fmaxf(mn, mPart[i][q_]);
    if (t < KTA && kt + 1 < NT2) {
      kn2s[t] = knv;
      khs[t] = sqrtf(knv + 1e-6f);
    }
    const v2f mnv = {mn, mn};
    float pv[8];
    v2f psv = {0.f, 0.f};
#pragma unroll
    for (int rp = 0; rp < 4; ++rp) {
      v2f d = svv[rp] - mnv;
      v2f p2 = {__expf(d.x), __expf(d.y)};
      pv[2 * rp] = p2.x;
      pv[2 * rp + 1] = p2.y;
      psv += p2;
    }
    float ps = psv.x + psv.y;
    ps += __shfl_xor(ps, 32);
    if (lh == 0) sPart[w][q_] = ps;
    if (w == 0 && lh == 0) {
      mbuf[(kt & 1) ^ 1][q_] = mn;
      fL[q_] = __expf(mold - mn);
    }
    {
      f16x2 p01 = {(f16)pv[0], (f16)pv[1]};
      f16x2 p23 = {(f16)pv[2], (f16)pv[3]};
      f16x2 p45 = {(f16)pv[4], (f16)pv[5]};
      f16x2 p67 = {(f16)pv[6], (f16)pv[7]};
      *(f16x2*)&Plds[2 * w + 0][q_][4 * lh + 0] = p01;
      *(f16x2*)&Plds[2 * w + 0][q_][4 * lh + 2] = p23;
      *(f16x2*)&Plds[2 * w + 1][q_][4 * lh + 0] = p45;
      *(f16x2*)&Plds[2 * w + 1][q_][4 * lh + 2] = p67;
    }
    __syncthreads();  // bar2

    // ---- PV ----
    {
      // fL rows: (r&3) + 8*(r>>2) + 4*lh -> four float4 groups
      float4 f0 = *(const float4*)&fL[0 + 4 * lh];
      float4 f1 = *(const float4*)&fL[8 + 4 * lh];
      float4 f2 = *(const float4*)&fL[16 + 4 * lh];
      float4 f3 = *(const float4*)&fL[24 + 4 * lh];
      acc[0] *= f0.x; acc[1] *= f0.y; acc[2] *= f0.z; acc[3] *= f0.w;
      acc[4] *= f1.x; acc[5] *= f1.y; acc[6] *= f1.z; acc[7] *= f1.w;
      acc[8] *= f2.x; acc[9] *= f2.y; acc[10] *= f2.z; acc[11] *= f2.w;
      acc[12] *= f3.x; acc[13] *= f3.y; acc[14] *= f3.z; acc[15] *= f3.w;
    }
    if (w == 0 && lh == 0) {
      float s8 = 0.f;
#pragma unroll
      for (int i = 0; i < 8; ++i) s8 += sPart[i][q_];
      lreg = lreg * fL[q_] + s8;
    }
#pragma unroll
    for (int ks = 0; ks < 8; ++ks) {
      f16x8 pa = *(const f16x8*)&Plds[2 * ks + lh][q_][0];
      acc = __builtin_amdgcn_mfma_f32_32x32x16_f16(pa, bv[ks], acc, 0, 0, 0);
    }
    // prefetch next-tile V fragments
    if (kt + 1 < NT2) {
      const f16* vbn = vb_base + (k0 + KTA);
#pragma unroll
      for (int ks = 0; ks < 8; ++ks) bv[ks] = *(const f16x8*)(vbn + ks * 16);
    }
  }

  if (w == 0 && lh == 0) lfin[q_] = 1.f / lreg;
  __syncthreads();
  const size_t obase = ((size_t)b * S_ + q0) * D_ + h * DK_ + w * 32 + q_;
#pragma unroll
  for (int r = 0; r < 16; ++r) {
    const int row = (r & 3) + 8 * (r >> 2) + 4 * lh;
    attn_out[obase + (size_t)row * D_] = (f16)(acc[r] * lfin[row]);
  }
}

// ---------------- output projection: LDS-staged f16 MFMA GEMM ----------------
__global__ __launch_bounds__(256, 1) void k_wo(const f16* __restrict__ A,
                                               const f16* __restrict__ Wt,
                                               const float* __restrict__ bias,
                                               float* __restrict__ C) {
  __shared__ __align__(16) f16 Abuf[2][128 * 64];
  __shared__ __align__(16) f16 Bbuf[2][128 * 64];
  const int t = threadIdx.x;
  const int w = t >> 6, lane = t & 63;
  const int wr = w >> 1, wc = w & 1;
  const int brow = blockIdx.y * 128, bcol = blockIdx.x * 128;

  int srow[4], skof[4];
#pragma unroll
  for (int u = 0; u < 4; ++u) {
    int c = t + 256 * u;
    int sub = c >> 6, l6 = c & 63;
    srow[u] = (sub >> 2) * 32 + (l6 & 31);
    skof[u] = (sub & 3) * 16 + (l6 >> 5) * 8;
  }

  uint4 ra0, ra1, ra2, ra3, rb0, rb1, rb2, rb3;
#define LOAD_TILE(K0)                                                        \
  {                                                                          \
    ra0 = *(const uint4*)(A + (size_t)(brow + srow[0]) * D_ + (K0) + skof[0]); \
    ra1 = *(const uint4*)(A + (size_t)(brow + srow[1]) * D_ + (K0) + skof[1]); \
    ra2 = *(const uint4*)(A + (size_t)(brow + srow[2]) * D_ + (K0) + skof[2]); \
    ra3 = *(const uint4*)(A + (size_t)(brow + srow[3]) * D_ + (K0) + skof[3]); \
    rb0 = *(const uint4*)(Wt + (size_t)(bcol + srow[0]) * D_ + (K0) + skof[0]); \
    rb1 = *(const uint4*)(Wt + (size_t)(bcol + srow[1]) * D_ + (K0) + skof[1]); \
    rb2 = *(const uint4*)(Wt + (size_t)(bcol + srow[2]) * D_ + (K0) + skof[2]); \
    rb3 = *(const uint4*)(Wt + (size_t)(bcol + srow[3]) * D_ + (K0) + skof[3]); \
  }
#define WRITE_TILE(BUF)                                       \
  {                                                           \
    *(uint4*)&Abuf[BUF][(t + 0) * 8] = ra0;                   \
    *(uint4*)&Abuf[BUF][(t + 256) * 8] = ra1;                 \
    *(uint4*)&Abuf[BUF][(t + 512) * 8] = ra2;                 \
    *(uint4*)&Abuf[BUF][(t + 768) * 8] = ra3;                 \
    *(uint4*)&Bbuf[BUF][(t + 0) * 8] = rb0;                   \
    *(uint4*)&Bbuf[BUF][(t + 256) * 8] = rb1;                 \
    *(uint4*)&Bbuf[BUF][(t + 512) * 8] = rb2;                 \
    *(uint4*)&Bbuf[BUF][(t + 768) * 8] = rb3;                 \
  }

  f32x16 acc00{}, acc01{}, acc10{}, acc11{};

  LOAD_TILE(0);
  WRITE_TILE(0);
  LOAD_TILE(64);
  __syncthreads();

  int cur = 0;
  for (int kt = 0; kt < 16; ++kt) {
    const int am0 = (wr * 2 + 0) * 4, am1 = (wr * 2 + 1) * 4;
    const int bn0 = (wc * 2 + 0) * 4, bn1 = (wc * 2 + 1) * 4;
#pragma unroll
    for (int kk = 0; kk < 4; ++kk) {
      f16x8 a0 = *(const f16x8*)&Abuf[cur][(am0 + kk) * 512 + lane * 8];
      f16x8 a1 = *(const f16x8*)&Abuf[cur][(am1 + kk) * 512 + lane * 8];
      f16x8 b0 = *(const f16x8*)&Bbuf[cur][(bn0 + kk) * 512 + lane * 8];
      f16x8 b1 = *(const f16x8*)&Bbuf[cur][(bn1 + kk) * 512 + lane * 8];
      acc00 = __builtin_amdgcn_mfma_f32_32x32x16_f16(a0, b0, acc00, 0, 0, 0);
      acc01 = __builtin_amdgcn_mfma_f32_32x32x16_f16(a0, b1, acc01, 0, 0, 0);
      acc10 = __builtin_amdgcn_mfma_f32_32x32x16_f16(a1, b0, acc10, 0, 0, 0);
      acc11 = __builtin_amdgcn_mfma_f32_32x32x16_f16(a1, b1, acc11, 0, 0, 0);
    }
    if (kt + 1 < 16) {
      WRITE_TILE(cur ^ 1);
      if (kt + 2 < 16) LOAD_TILE((kt + 2) * 64);
    }
    __syncthreads();
    cur ^= 1;
  }

  const int l31 = lane & 31, lh = lane >> 5;
  const float bv0 = bias[bcol + (wc * 2 + 0) * 32 + l31];
  const float bv1 = bias[bcol + (wc * 2 + 1) * 32 + l31];
#pragma unroll
  for (int r = 0; r < 16; ++r) {
    const int row = (r & 3) + 8 * (r >> 2) + 4 * lh;
    const size_t m0r = (size_t)(brow + (wr * 2 + 0) * 32 + row) * D_;
    const size_t m1r = (size_t)(brow + (wr * 2 + 1) * 32 + row) * D_;
    C[m0r + bcol + (wc * 2 + 0) * 32 + l31] = acc00[r] + bv0;
    C[m0r + bcol + (wc * 2 + 1) * 32 + l31] = acc01[r] + bv1;
    C[m1r + bcol + (wc * 2 + 0) * 32 + l31] = acc10[r] + bv0;
    C[m1r + bcol + (wc * 2 + 1) * 32 + l31] = acc11[r] + bv1;
  }
#undef LOAD_TILE
#undef WRITE_TILE
}

extern "C" void kernel_launch(void* const* d_in, const int* in_sizes, int n_in,
                              void* d_out, int out_size, void* d_ws, size_t ws_size,
                              hipStream_t stream) {
  const float* Q_input = (const float*)d_in[0];
  const float* K = (const float*)d_in[1];
  const float* V = (const float*)d_in[2];
  const float* Wq_w = (const float*)d_in[4];
  const float* Wq_b = (const float*)d_in[5];
  const float* Wo_w = (const float*)d_in[6];
  const float* Wo_b = (const float*)d_in[7];
  const float* proj_w = (const float*)d_in[8];
  const float* proj_b = (const float*)d_in[9];
  const float* geo_w = (const float*)d_in[10];
  const float* temp = (const float*)d_in[11];

  float* ws = (float*)d_ws;
  float* M = ws;                          // 98304 f32 ([hj][d])
  float* cbias = M + 98304;               // 128
  float* qn2 = cbias + 128;               // 16384
  float* kn2 = qn2 + 16384;               // 16384
  f16* pqF = (f16*)(kn2 + 16384);
  f16* pkF = (f16*)(kn2 + 16384 + 131072);
  f16* Vt = (f16*)(kn2 + 16384 + 262144);
  f16* attnF = (f16*)(kn2 + 16384 + 262144 + 2097152);
  f16* Wf = (f16*)(kn2 + 16384 + 262144 + 2097152 + 2097152);
  float* out = (float*)d_out;

  k_fuse<<<dim3(384), dim3(256), 0, stream>>>(Wq_w, proj_w, M);
  k_fuse_bias<<<dim3(1), dim3(128), 0, stream>>>(Wq_b, proj_w, proj_b, cbias);
  k_wcvt<<<dim3(512), dim3(256), 0, stream>>>(Wo_w, Wf);
  k_vt<<<dim3(32, 4, 8), dim3(256), 0, stream>>>(V, Vt);
  k_genqk<<<dim3(1024), dim3(128), 0, stream>>>(Q_input, K, M, cbias, proj_w,
                                                proj_b, pqF, qn2, pkF, kn2);
  k_attn<<<dim3(512), dim3(512), 0, stream>>>(pqF, qn2, pkF, kn2, Vt, geo_w, temp, attnF);
  k_wo<<<dim3(8, 32), dim3(256), 0, stream>>>(attnF, Wf, Wo_b, out);
}